// Round 4
// baseline (380.959 us; speedup 1.0000x reference)
//
#include <hip/hip_runtime.h>
#include <math.h>

#define B_   8
#define S_   512
#define DM_  768
#define H_   12
#define D_   64
#define BH_  96
#define M_   4096   // B_*S_

typedef _Float16 f16x8 __attribute__((ext_vector_type(8)));
typedef float    f32x4 __attribute__((ext_vector_type(4)));

__device__ __forceinline__ float dual_spike(float x) {
    return x >= 1.0f ? 1.0f : (x <= -1.0f ? -1.0f : 0.0f);
}

// ---------------- Prepass: X -> fp16 hi/lo planes, fragment-major tile order ----
// Layout: [mb 32][kc 24][fm 8][g 4][r 16][j 8] halves. One wave per (mb,kc,fm).
__global__ __launch_bounds__(256) void prep_x(
    const float* __restrict__ X, _Float16* __restrict__ Xh, _Float16* __restrict__ Xl)
{
    int wid  = blockIdx.x * 4 + (threadIdx.x >> 6);
    int lane = threadIdx.x & 63;
    int fm = wid & 7, kc = (wid >> 3) % 24, mb = wid / 192;
    int row = mb * 128 + fm * 16 + (lane & 15);
    int col = kc * 32 + (lane >> 4) * 8;
    const float4* p = reinterpret_cast<const float4*>(&X[row * DM_ + col]);
    float4 x0 = p[0], x1 = p[1];
    float xs[8] = {x0.x, x0.y, x0.z, x0.w, x1.x, x1.y, x1.z, x1.w};
    f16x8 hi, lo;
    #pragma unroll
    for (int j = 0; j < 8; ++j) {
        float v = xs[j] * 256.0f;           // exact scale for fp16 denorm headroom
        _Float16 h = (_Float16)v;
        hi[j] = h;
        lo[j] = (_Float16)(v - (float)h);
    }
    size_t out = ((size_t)wid * 64 + lane) * 8;
    *reinterpret_cast<f16x8*>(&Xh[out]) = hi;
    *reinterpret_cast<f16x8*>(&Xl[out]) = lo;
}

// ---------------- Prepass: W (q,k,v) -> transposed fp16 hi/lo planes ------------
// Layout: [which 3][nb 6][kc 24][fn 8][g 4][c 16][j 8] halves. Wave per (which,nb,kc,fn).
__global__ __launch_bounds__(256) void prep_w(
    const float* __restrict__ Wq, const float* __restrict__ Wk, const float* __restrict__ Wv,
    _Float16* __restrict__ Wth, _Float16* __restrict__ Wtl)
{
    int wid  = blockIdx.x * 4 + (threadIdx.x >> 6);
    int lane = threadIdx.x & 63;
    int fn = wid & 7, kc = (wid >> 3) % 24;
    int nb = (wid >> 3) / 24 % 6, which = wid / 1152;
    const float* __restrict__ W = which == 0 ? Wq : (which == 1 ? Wk : Wv);
    int c = lane & 15, g = lane >> 4;
    int ncol = nb * 128 + fn * 16 + c;
    int krow = kc * 32 + g * 8;
    f16x8 hi, lo;
    #pragma unroll
    for (int j = 0; j < 8; ++j) {
        float v = W[(krow + j) * DM_ + ncol] * 256.0f;
        _Float16 h = (_Float16)v;
        hi[j] = h;
        lo[j] = (_Float16)(v - (float)h);
    }
    size_t out = ((size_t)wid * 64 + lane) * 8;
    *reinterpret_cast<f16x8*>(&Wth[out]) = hi;
    *reinterpret_cast<f16x8*>(&Wtl[out]) = lo;
}

// ---------------- Kernel 1: QKV projections via fp16 split MFMA ----------------
// v4: NO LDS, NO barriers. Fragments load global->VGPR directly (prep arrays are
// fragment-major). Register double-buffer: load(kc+1) overlaps MFMA(kc).
// 128x128 tile, 4 waves (2x2), each wave 64x64 (4x4 frags of 16x16x32).
// acc = Ahi*Bhi + Ahi*Blo + Alo*Bhi ; val = acc/65536 + bias.
__global__ __launch_bounds__(256, 2) void qkv_mfma(
    const _Float16* __restrict__ Xh, const _Float16* __restrict__ Xl,
    const _Float16* __restrict__ Wth, const _Float16* __restrict__ Wtl,
    const float* __restrict__ X,
    const float* __restrict__ Wq, const float* __restrict__ bq,
    const float* __restrict__ Wk, const float* __restrict__ bk,
    const float* __restrict__ Wv, const float* __restrict__ bv,
    float* __restrict__ q, float* __restrict__ k, float* __restrict__ v)
{
    // XCD-bijective swizzle: nwg = 576 = 8 * 72; each XCD gets a contiguous
    // which-major chunk; nb is innermost so the A panel (393 KB) is reused by
    // 6 consecutive blocks -> per-XCD L2 working set ~2.8 MB.
    const int orig = blockIdx.x;
    const int wg = (orig & 7) * 72 + (orig >> 3);
    const int which = wg / 192;
    const int rem = wg % 192;
    const int mb = rem / 6, nb = rem % 6;

    const float* __restrict__ bias = which == 0 ? bq : (which == 1 ? bk : bv);
    float* __restrict__ out        = which == 0 ? q  : (which == 1 ? k  : v);

    const int tid = threadIdx.x;
    const int wave = tid >> 6, lane = tid & 63;
    const int wm = wave >> 1, wn = wave & 1;
    const int l15 = lane & 15, g = lane >> 4;

    // per-lane fragment base addresses (fragment f: +f*512 halves; kc: +4096)
    const _Float16* __restrict__ pAh = Xh + (size_t)(mb * 24) * 4096 + wm * 2048 + g * 128 + l15 * 8;
    const _Float16* __restrict__ pAl = Xl + (size_t)(mb * 24) * 4096 + wm * 2048 + g * 128 + l15 * 8;
    const _Float16* __restrict__ pBh = Wth + (size_t)((which * 6 + nb) * 24) * 4096 + wn * 2048 + g * 128 + l15 * 8;
    const _Float16* __restrict__ pBl = Wtl + (size_t)((which * 6 + nb) * 24) * 4096 + wn * 2048 + g * 128 + l15 * 8;

    f32x4 acc[4][4];
    #pragma unroll
    for (int i = 0; i < 4; ++i)
        #pragma unroll
        for (int j = 0; j < 4; ++j) acc[i][j] = (f32x4){0.f, 0.f, 0.f, 0.f};

    // two named register buffers (static indexing only -> no scratch)
    f16x8 a0h[4], a0l[4], b0h[4], b0l[4];
    f16x8 a1h[4], a1l[4], b1h[4], b1l[4];

    auto loadfrag = [&](int kc, f16x8 (&ah)[4], f16x8 (&al)[4],
                                f16x8 (&bh)[4], f16x8 (&bl)[4]) {
        const size_t o = (size_t)kc * 4096;
        #pragma unroll
        for (int f = 0; f < 4; ++f) {
            ah[f] = *reinterpret_cast<const f16x8*>(pAh + o + f * 512);
            al[f] = *reinterpret_cast<const f16x8*>(pAl + o + f * 512);
            bh[f] = *reinterpret_cast<const f16x8*>(pBh + o + f * 512);
            bl[f] = *reinterpret_cast<const f16x8*>(pBl + o + f * 512);
        }
    };
    auto domfma = [&](f16x8 (&ah)[4], f16x8 (&al)[4],
                      f16x8 (&bh)[4], f16x8 (&bl)[4]) {
        #pragma unroll
        for (int i = 0; i < 4; ++i)
            #pragma unroll
            for (int j = 0; j < 4; ++j) {
                acc[i][j] = __builtin_amdgcn_mfma_f32_16x16x32_f16(ah[i], bh[j], acc[i][j], 0, 0, 0);
                acc[i][j] = __builtin_amdgcn_mfma_f32_16x16x32_f16(ah[i], bl[j], acc[i][j], 0, 0, 0);
                acc[i][j] = __builtin_amdgcn_mfma_f32_16x16x32_f16(al[i], bh[j], acc[i][j], 0, 0, 0);
            }
    };

    loadfrag(0, a0h, a0l, b0h, b0l);
    for (int kc2 = 0; kc2 < 12; ++kc2) {
        loadfrag(2 * kc2 + 1, a1h, a1l, b1h, b1l);   // prefetch odd tile
        domfma(a0h, a0l, b0h, b0l);                  // compute even tile
        if (kc2 < 11)
            loadfrag(2 * kc2 + 2, a0h, a0l, b0h, b0l); // prefetch next even
        domfma(a1h, a1l, b1h, b1l);                  // compute odd tile
    }

    const float* __restrict__ Worig = which == 0 ? Wq : (which == 1 ? Wk : Wv);
    #pragma unroll
    for (int i = 0; i < 4; ++i) {
        #pragma unroll
        for (int j = 0; j < 4; ++j) {
            int n = nb * 128 + wn * 64 + j * 16 + l15;
            int h = n >> 6, d = n & 63;
            float bn = bias[n];
            #pragma unroll
            for (int r = 0; r < 4; ++r) {
                int m = mb * 128 + wm * 64 + i * 16 + g * 4 + r;
                float val = acc[i][j][r] * (1.0f / 65536.0f) + bn;
                if (which < 2) {
                    // near spike-threshold: recompute with the exact sequential
                    // fp32 chain (bit-identical to the validated R1 kernel).
                    if (fabsf(fabsf(val) - 1.0f) < 1e-4f) {
                        float a2 = 0.0f;
                        for (int kk = 0; kk < DM_; ++kk)
                            a2 = fmaf(X[m * DM_ + kk], Worig[kk * DM_ + n], a2);
                        val = a2 + bn;
                    }
                }
                if (which == 0)      val = dual_spike(val);
                else if (which == 1) val = 0.5f * dual_spike(val) + 0.5f * val;
                int b = m >> 9, s = m & 511;
                out[(((b * H_ + h) * S_) + s) * D_ + d] = val;
            }
        }
    }
}

// ---------------- Kernel 2: score threshold counts ----------------
__global__ __launch_bounds__(256) void score_sums(
    const float* __restrict__ q, const float* __restrict__ k,
    float* __restrict__ xh, float* __restrict__ xw)
{
    __shared__ __align__(16) float Qt[64][68];
    __shared__ __align__(16) float Kt[64][68];
    __shared__ float colred[16][64];

    const int bh = blockIdx.z;
    const int q0 = blockIdx.y * 64, k0 = blockIdx.x * 64;
    const int tid = threadIdx.x, tx = tid & 15, ty = tid >> 4;
    const float* __restrict__ qb = q + bh * S_ * D_;
    const float* __restrict__ kb = k + bh * S_ * D_;

    #pragma unroll
    for (int t = 0; t < 4; ++t) {
        int e = tid + t * 256;
        int r = e >> 4, c4 = (e & 15) << 2;
        const float4 qv = *reinterpret_cast<const float4*>(&qb[(q0 + r) * D_ + c4]);
        Qt[c4+0][r] = qv.x; Qt[c4+1][r] = qv.y; Qt[c4+2][r] = qv.z; Qt[c4+3][r] = qv.w;
        const float4 kv = *reinterpret_cast<const float4*>(&kb[(k0 + r) * D_ + c4]);
        Kt[c4+0][r] = kv.x; Kt[c4+1][r] = kv.y; Kt[c4+2][r] = kv.z; Kt[c4+3][r] = kv.w;
    }
    __syncthreads();

    float dot[4][4];
    #pragma unroll
    for (int i = 0; i < 4; ++i)
        #pragma unroll
        for (int j = 0; j < 4; ++j) dot[i][j] = 0.0f;

    for (int d = 0; d < 64; ++d) {
        float4 av = *reinterpret_cast<const float4*>(&Qt[d][ty * 4]);
        float4 bv = *reinterpret_cast<const float4*>(&Kt[d][tx * 4]);
        float a[4] = {av.x, av.y, av.z, av.w};
        float b[4] = {bv.x, bv.y, bv.z, bv.w};
        #pragma unroll
        for (int i = 0; i < 4; ++i)
            #pragma unroll
            for (int j = 0; j < 4; ++j)
                dot[i][j] = fmaf(a[i], b[j], dot[i][j]);
    }

    float rowc[4] = {0,0,0,0}, colc[4] = {0,0,0,0};
    #pragma unroll
    for (int i = 0; i < 4; ++i)
        #pragma unroll
        for (int j = 0; j < 4; ++j) {
            float t1 = dot[i][j] >= 8.0f ? 1.0f : 0.0f;
            rowc[i] += t1; colc[j] += t1;
        }
    #pragma unroll
    for (int i = 0; i < 4; ++i) {
        float rsum = rowc[i];
        for (int o = 1; o < 16; o <<= 1) rsum += __shfl_xor(rsum, o, 16);
        if (tx == 0) atomicAdd(&xh[bh * S_ + q0 + ty * 4 + i], rsum);
    }
    #pragma unroll
    for (int j = 0; j < 4; ++j) colred[ty][tx * 4 + j] = colc[j];
    __syncthreads();
    if (tid < 64) {
        float ssum = 0.0f;
        #pragma unroll
        for (int t = 0; t < 16; ++t) ssum += colred[t][tid];
        atomicAdd(&xw[bh * S_ + k0 + tid], ssum);
    }
}

// ---------------- Kernel 3: tiny conv / batchnorm / sigmoid ----------------
__global__ __launch_bounds__(1024) void small_ops(
    const float* __restrict__ xh, const float* __restrict__ xw,
    const float* __restrict__ c1w, const float* __restrict__ gamma,
    const float* __restrict__ beta, const float* __restrict__ chw,
    const float* __restrict__ cww,
    float* __restrict__ y, float* __restrict__ s_h, float* __restrict__ s_w)
{
    const int tid = threadIdx.x;
    __shared__ float red[1024];
    __shared__ float c1s[36], chs[36], cws[36];
    __shared__ float mu_s[3], rs_s[3];
    if (tid < 36) { c1s[tid] = c1w[tid]; chs[tid] = chw[tid]; cws[tid] = cww[tid]; }
    __syncthreads();

    for (int e = tid; e < B_ * 3 * 1024; e += 1024) {
        int n = e & 1023; int br = e >> 10; int r = br % 3; int b = br / 3;
        float acc = 0.0f;
        #pragma unroll
        for (int h = 0; h < 12; ++h) {
            float cv = (n < 512) ? xh[(b * H_ + h) * S_ + n]
                                 : xw[(b * H_ + h) * S_ + (n - 512)];
            acc = fmaf(c1s[r * 12 + h], cv * (1.0f / 512.0f), acc);
        }
        y[e] = acc;
    }
    __syncthreads();

    for (int r = 0; r < 3; ++r) {
        float s = 0.0f;
        for (int e = tid; e < 8192; e += 1024) {
            int b = e >> 10, n = e & 1023;
            s += y[((b * 3 + r) << 10) | n];
        }
        red[tid] = s; __syncthreads();
        for (int o = 512; o > 0; o >>= 1) { if (tid < o) red[tid] += red[tid + o]; __syncthreads(); }
        if (tid == 0) mu_s[r] = red[0] * (1.0f / 8192.0f);
        __syncthreads();
    }
    for (int r = 0; r < 3; ++r) {
        float mu = mu_s[r]; float s = 0.0f;
        for (int e = tid; e < 8192; e += 1024) {
            int b = e >> 10, n = e & 1023;
            float d = y[((b * 3 + r) << 10) | n] - mu;
            s = fmaf(d, d, s);
        }
        red[tid] = s; __syncthreads();
        for (int o = 512; o > 0; o >>= 1) { if (tid < o) red[tid] += red[tid + o]; __syncthreads(); }
        if (tid == 0) rs_s[r] = rsqrtf(red[0] * (1.0f / 8192.0f) + 1e-5f);
        __syncthreads();
    }
    for (int e = tid; e < B_ * H_ * S_; e += 1024) {
        int s = e & 511; int bh = e >> 9; int h = bh % H_; int b = bh / H_;
        float ah = 0.0f, aw = 0.0f;
        #pragma unroll
        for (int r = 0; r < 3; ++r) {
            int yb = (b * 3 + r) << 10;
            float yh = fmaxf((y[yb + s]       - mu_s[r]) * rs_s[r] * gamma[r] + beta[r], 0.0f);
            float yw = fmaxf((y[yb + 512 + s] - mu_s[r]) * rs_s[r] * gamma[r] + beta[r], 0.0f);
            ah = fmaf(chs[h * 3 + r], yh, ah);
            aw = fmaf(cws[h * 3 + r], yw, aw);
        }
        s_h[e] = 1.0f / (1.0f + expf(-ah));
        s_w[e] = 1.0f / (1.0f + expf(-aw));
    }
}

// ---------------- Kernel 4: recompute scores + bias + online softmax + PV ------
__global__ __launch_bounds__(256) void attn_pv(
    const float* __restrict__ q, const float* __restrict__ k,
    const float* __restrict__ v, const float* __restrict__ mask,
    const float* __restrict__ s_h, const float* __restrict__ s_w,
    float* __restrict__ out)
{
    __shared__ __align__(16) float Qt[64][68];
    __shared__ __align__(16) float Kt[64][68];
    __shared__ __align__(16) float Vs[64][68];

    const int bh = blockIdx.y;
    const int b = bh / H_, h = bh % H_;
    const int q0 = blockIdx.x * 64;
    const int tid = threadIdx.x, tx = tid & 15, ty = tid >> 4;
    const float* __restrict__ qb = q + bh * S_ * D_;
    const float* __restrict__ kb = k + bh * S_ * D_;
    const float* __restrict__ vb = v + bh * S_ * D_;

    #pragma unroll
    for (int t = 0; t < 4; ++t) {
        int e = tid + t * 256;
        int r = e >> 4, c4 = (e & 15) << 2;
        const float4 qv = *reinterpret_cast<const float4*>(&qb[(q0 + r) * D_ + c4]);
        Qt[c4+0][r] = qv.x; Qt[c4+1][r] = qv.y; Qt[c4+2][r] = qv.z; Qt[c4+3][r] = qv.w;
    }
    float shq[4];
    #pragma unroll
    for (int i = 0; i < 4; ++i) shq[i] = s_h[bh * S_ + q0 + ty * 4 + i];

    float m_r[4], l_r[4], ctx[4][4];
    #pragma unroll
    for (int i = 0; i < 4; ++i) {
        m_r[i] = -INFINITY; l_r[i] = 0.0f;
        #pragma unroll
        for (int j = 0; j < 4; ++j) ctx[i][j] = 0.0f;
    }

    for (int k0 = 0; k0 < S_; k0 += 64) {
        __syncthreads();
        #pragma unroll
        for (int t = 0; t < 4; ++t) {
            int e = tid + t * 256;
            int r = e >> 4, c4 = (e & 15) << 2;
            const float4 kv = *reinterpret_cast<const float4*>(&kb[(k0 + r) * D_ + c4]);
            Kt[c4+0][r] = kv.x; Kt[c4+1][r] = kv.y; Kt[c4+2][r] = kv.z; Kt[c4+3][r] = kv.w;
            *reinterpret_cast<float4*>(&Vs[r][c4]) =
                *reinterpret_cast<const float4*>(&vb[(k0 + r) * D_ + c4]);
        }
        __syncthreads();

        float dot[4][4];
        #pragma unroll
        for (int i = 0; i < 4; ++i)
            #pragma unroll
            for (int j = 0; j < 4; ++j) dot[i][j] = 0.0f;
        for (int d = 0; d < 64; ++d) {
            float4 av = *reinterpret_cast<const float4*>(&Qt[d][ty * 4]);
            float4 bv = *reinterpret_cast<const float4*>(&Kt[d][tx * 4]);
            float a[4] = {av.x, av.y, av.z, av.w};
            float bb[4] = {bv.x, bv.y, bv.z, bv.w};
            #pragma unroll
            for (int i = 0; i < 4; ++i)
                #pragma unroll
                for (int j = 0; j < 4; ++j)
                    dot[i][j] = fmaf(a[i], bb[j], dot[i][j]);
        }

        float swj[4], mj[4];
        #pragma unroll
        for (int j = 0; j < 4; ++j) {
            swj[j] = s_w[bh * S_ + k0 + tx * 4 + j];
            mj[j]  = mask[b * S_ + k0 + tx * 4 + j];
        }
        float sc[4][4];
        #pragma unroll
        for (int i = 0; i < 4; ++i)
            #pragma unroll
            for (int j = 0; j < 4; ++j) {
                float t1 = dot[i][j] >= 8.0f ? 1.0f : 0.0f;
                sc[i][j] = (dot[i][j] * 0.125f + mj[j]) + t1 * (shq[i] * swj[j]);
            }

        float p[4][4], cscale[4];
        #pragma unroll
        for (int i = 0; i < 4; ++i) {
            float tmax = fmaxf(fmaxf(sc[i][0], sc[i][1]), fmaxf(sc[i][2], sc[i][3]));
            for (int o = 1; o < 16; o <<= 1) tmax = fmaxf(tmax, __shfl_xor(tmax, o, 16));
            float mn = fmaxf(m_r[i], tmax);
            float ps = 0.0f;
            #pragma unroll
            for (int j = 0; j < 4; ++j) { p[i][j] = expf(sc[i][j] - mn); ps += p[i][j]; }
            for (int o = 1; o < 16; o <<= 1) ps += __shfl_xor(ps, o, 16);
            float scale = expf(m_r[i] - mn);
            l_r[i] = l_r[i] * scale + ps;
            m_r[i] = mn;
            cscale[i] = scale;
        }
        __syncthreads();
        #pragma unroll
        for (int i = 0; i < 4; ++i)
            #pragma unroll
            for (int j = 0; j < 4; ++j)
                Kt[ty * 4 + i][tx * 4 + j] = p[i][j];
        __syncthreads();
        #pragma unroll
        for (int i = 0; i < 4; ++i)
            #pragma unroll
            for (int j = 0; j < 4; ++j) ctx[i][j] *= cscale[i];
        for (int kk = 0; kk < 64; ++kk) {
            float4 vv = *reinterpret_cast<const float4*>(&Vs[kk][tx * 4]);
            float pv0 = Kt[ty*4+0][kk], pv1 = Kt[ty*4+1][kk];
            float pv2 = Kt[ty*4+2][kk], pv3 = Kt[ty*4+3][kk];
            ctx[0][0] = fmaf(pv0, vv.x, ctx[0][0]); ctx[0][1] = fmaf(pv0, vv.y, ctx[0][1]);
            ctx[0][2] = fmaf(pv0, vv.z, ctx[0][2]); ctx[0][3] = fmaf(pv0, vv.w, ctx[0][3]);
            ctx[1][0] = fmaf(pv1, vv.x, ctx[1][0]); ctx[1][1] = fmaf(pv1, vv.y, ctx[1][1]);
            ctx[1][2] = fmaf(pv1, vv.z, ctx[1][2]); ctx[1][3] = fmaf(pv1, vv.w, ctx[1][3]);
            ctx[2][0] = fmaf(pv2, vv.x, ctx[2][0]); ctx[2][1] = fmaf(pv2, vv.y, ctx[2][1]);
            ctx[2][2] = fmaf(pv2, vv.z, ctx[2][2]); ctx[2][3] = fmaf(pv2, vv.w, ctx[2][3]);
            ctx[3][0] = fmaf(pv3, vv.x, ctx[3][0]); ctx[3][1] = fmaf(pv3, vv.y, ctx[3][1]);
            ctx[3][2] = fmaf(pv3, vv.z, ctx[3][2]); ctx[3][3] = fmaf(pv3, vv.w, ctx[3][3]);
        }
    }
    #pragma unroll
    for (int i = 0; i < 4; ++i) {
        int s = q0 + ty * 4 + i;
        float inv = 1.0f / l_r[i];
        float4 o;
        o.x = ctx[i][0] * inv; o.y = ctx[i][1] * inv;
        o.z = ctx[i][2] * inv; o.w = ctx[i][3] * inv;
        *reinterpret_cast<float4*>(&out[(b * S_ + s) * DM_ + h * D_ + tx * 4]) = o;
    }
}

extern "C" void kernel_launch(void* const* d_in, const int* in_sizes, int n_in,
                              void* d_out, int out_size, void* d_ws, size_t ws_size,
                              hipStream_t stream) {
    const float* X    = (const float*)d_in[0];
    const float* mask = (const float*)d_in[1];
    const float* Wq   = (const float*)d_in[2];
    const float* bq   = (const float*)d_in[3];
    const float* Wk   = (const float*)d_in[4];
    const float* bk   = (const float*)d_in[5];
    const float* Wv   = (const float*)d_in[6];
    const float* bv   = (const float*)d_in[7];
    const float* c1w  = (const float*)d_in[8];
    const float* gam  = (const float*)d_in[9];
    const float* bet  = (const float*)d_in[10];
    const float* chw  = (const float*)d_in[11];
    const float* cww  = (const float*)d_in[12];
    float* out = (float*)d_out;

    float* ws = (float*)d_ws;
    float* q  = ws;                        // 3145728 f32
    float* k  = q  + 3145728;
    float* v  = k  + 3145728;
    float* xh = v  + 3145728;              // 49152
    float* xw = xh + 49152;
    float* y  = xw + 49152;                // 24576
    float* sh = y  + 24576;
    float* sw = sh + 49152;
    _Float16* Xh  = (_Float16*)(sw + 49152);   // 3145728 halves
    _Float16* Xl  = Xh + 3145728;
    _Float16* Wth = Xl + 3145728;              // 1769472 halves
    _Float16* Wtl = Wth + 1769472;             // total ws ~55.6 MiB

    hipMemsetAsync(xh, 0, 2 * 49152 * sizeof(float), stream);

    prep_x<<<1536, 256, 0, stream>>>(X, Xh, Xl);
    prep_w<<<864, 256, 0, stream>>>(Wq, Wk, Wv, Wth, Wtl);
    qkv_mfma<<<576, 256, 0, stream>>>(Xh, Xl, Wth, Wtl,
        X, Wq, bq, Wk, bk, Wv, bv, q, k, v);
    score_sums<<<dim3(8, 8, 96), 256, 0, stream>>>(q, k, xh, xw);
    small_ops<<<1, 1024, 0, stream>>>(xh, xw, c1w, gam, bet, chw, cww, y, sh, sw);
    attn_pv<<<dim3(8, 96), 256, 0, stream>>>(q, k, v, mask, sh, sw, out);
}

// Round 5
// 341.689 us; speedup vs baseline: 1.1149x; 1.1149x over previous
//
#include <hip/hip_runtime.h>
#include <math.h>

#define B_   8
#define S_   512
#define DM_  768
#define H_   12
#define D_   64
#define BH_  96
#define M_   4096   // B_*S_

typedef _Float16 f16x8 __attribute__((ext_vector_type(8)));
typedef float    f32x4 __attribute__((ext_vector_type(4)));

__device__ __forceinline__ float dual_spike(float x) {
    return x >= 1.0f ? 1.0f : (x <= -1.0f ? -1.0f : 0.0f);
}

// ---------------- Prepass: X -> fp16 hi/lo planes, fragment-major tile order ----
// Layout: [mb 32][kc 24][fm 8][g 4][r 16][j 8] halves. One wave per (mb,kc,fm).
__global__ __launch_bounds__(256) void prep_x(
    const float* __restrict__ X, _Float16* __restrict__ Xh, _Float16* __restrict__ Xl)
{
    int wid  = blockIdx.x * 4 + (threadIdx.x >> 6);
    int lane = threadIdx.x & 63;
    int fm = wid & 7, kc = (wid >> 3) % 24, mb = wid / 192;
    int row = mb * 128 + fm * 16 + (lane & 15);
    int col = kc * 32 + (lane >> 4) * 8;
    const float4* p = reinterpret_cast<const float4*>(&X[row * DM_ + col]);
    float4 x0 = p[0], x1 = p[1];
    float xs[8] = {x0.x, x0.y, x0.z, x0.w, x1.x, x1.y, x1.z, x1.w};
    f16x8 hi, lo;
    #pragma unroll
    for (int j = 0; j < 8; ++j) {
        float v = xs[j] * 256.0f;           // exact scale for fp16 denorm headroom
        _Float16 h = (_Float16)v;
        hi[j] = h;
        lo[j] = (_Float16)(v - (float)h);
    }
    size_t out = ((size_t)wid * 64 + lane) * 8;
    *reinterpret_cast<f16x8*>(&Xh[out]) = hi;
    *reinterpret_cast<f16x8*>(&Xl[out]) = lo;
}

// ---------------- Prepass: W (q,k,v) -> transposed fp16 hi/lo planes ------------
// Layout: [which 3][nb 6][kc 24][fn 8][g 4][c 16][j 8] halves. Wave per (which,nb,kc,fn).
__global__ __launch_bounds__(256) void prep_w(
    const float* __restrict__ Wq, const float* __restrict__ Wk, const float* __restrict__ Wv,
    _Float16* __restrict__ Wth, _Float16* __restrict__ Wtl)
{
    int wid  = blockIdx.x * 4 + (threadIdx.x >> 6);
    int lane = threadIdx.x & 63;
    int fn = wid & 7, kc = (wid >> 3) % 24;
    int nb = (wid >> 3) / 24 % 6, which = wid / 1152;
    const float* __restrict__ W = which == 0 ? Wq : (which == 1 ? Wk : Wv);
    int c = lane & 15, g = lane >> 4;
    int ncol = nb * 128 + fn * 16 + c;
    int krow = kc * 32 + g * 8;
    f16x8 hi, lo;
    #pragma unroll
    for (int j = 0; j < 8; ++j) {
        float v = W[(krow + j) * DM_ + ncol] * 256.0f;
        _Float16 h = (_Float16)v;
        hi[j] = h;
        lo[j] = (_Float16)(v - (float)h);
    }
    size_t out = ((size_t)wid * 64 + lane) * 8;
    *reinterpret_cast<f16x8*>(&Wth[out]) = hi;
    *reinterpret_cast<f16x8*>(&Wtl[out]) = lo;
}

// ---------------- Kernel 1: QKV projections via fp16 split MFMA ----------------
// v5: pure-register main loop (no barriers) + WAVE-COOPERATIVE spike fixup:
// flagged (m,n) dots are re-run with the exact R1 sequential fp32 chain, but the
// operands are staged X-row/W-col -> LDS by the whole wave first (parallel loads),
// so the chain is FMA-latency-bound (~3K cyc) instead of serial-cacheline-bound.
__global__ __launch_bounds__(256, 2) void qkv_mfma(
    const _Float16* __restrict__ Xh, const _Float16* __restrict__ Xl,
    const _Float16* __restrict__ Wth, const _Float16* __restrict__ Wtl,
    const float* __restrict__ X,
    const float* __restrict__ Wq, const float* __restrict__ bq,
    const float* __restrict__ Wk, const float* __restrict__ bk,
    const float* __restrict__ Wv, const float* __restrict__ bv,
    float* __restrict__ q, float* __restrict__ k, float* __restrict__ v)
{
    // XCD-bijective swizzle: nwg = 576 = 8 * 72; each XCD gets a contiguous
    // which-major chunk; nb innermost -> per-XCD L2 working set ~2.8 MB.
    const int orig = blockIdx.x;
    const int wg = (orig & 7) * 72 + (orig >> 3);
    const int which = wg / 192;
    const int rem = wg % 192;
    const int mb = rem / 6, nb = rem % 6;

    const float* __restrict__ bias = which == 0 ? bq : (which == 1 ? bk : bv);
    float* __restrict__ out        = which == 0 ? q  : (which == 1 ? k  : v);

    // per-wave fixup scratch: [wave][xrow 768 | wcol 768]
    __shared__ __align__(16) float fixs[4][1536];

    const int tid = threadIdx.x;
    const int wave = tid >> 6, lane = tid & 63;
    const int wm = wave >> 1, wn = wave & 1;
    const int l15 = lane & 15, g = lane >> 4;

    // per-lane fragment base addresses (fragment f: +f*512 halves; kc: +4096)
    const _Float16* __restrict__ pAh = Xh + (size_t)(mb * 24) * 4096 + wm * 2048 + g * 128 + l15 * 8;
    const _Float16* __restrict__ pAl = Xl + (size_t)(mb * 24) * 4096 + wm * 2048 + g * 128 + l15 * 8;
    const _Float16* __restrict__ pBh = Wth + (size_t)((which * 6 + nb) * 24) * 4096 + wn * 2048 + g * 128 + l15 * 8;
    const _Float16* __restrict__ pBl = Wtl + (size_t)((which * 6 + nb) * 24) * 4096 + wn * 2048 + g * 128 + l15 * 8;

    f32x4 acc[4][4];
    #pragma unroll
    for (int i = 0; i < 4; ++i)
        #pragma unroll
        for (int j = 0; j < 4; ++j) acc[i][j] = (f32x4){0.f, 0.f, 0.f, 0.f};

    f16x8 a0h[4], a0l[4], b0h[4], b0l[4];
    f16x8 a1h[4], a1l[4], b1h[4], b1l[4];

    auto loadfrag = [&](int kc, f16x8 (&ah)[4], f16x8 (&al)[4],
                                f16x8 (&bh)[4], f16x8 (&bl)[4]) {
        const size_t o = (size_t)kc * 4096;
        #pragma unroll
        for (int f = 0; f < 4; ++f) {
            ah[f] = *reinterpret_cast<const f16x8*>(pAh + o + f * 512);
            al[f] = *reinterpret_cast<const f16x8*>(pAl + o + f * 512);
            bh[f] = *reinterpret_cast<const f16x8*>(pBh + o + f * 512);
            bl[f] = *reinterpret_cast<const f16x8*>(pBl + o + f * 512);
        }
    };
    auto domfma = [&](f16x8 (&ah)[4], f16x8 (&al)[4],
                      f16x8 (&bh)[4], f16x8 (&bl)[4]) {
        #pragma unroll
        for (int i = 0; i < 4; ++i)
            #pragma unroll
            for (int j = 0; j < 4; ++j) {
                acc[i][j] = __builtin_amdgcn_mfma_f32_16x16x32_f16(ah[i], bh[j], acc[i][j], 0, 0, 0);
                acc[i][j] = __builtin_amdgcn_mfma_f32_16x16x32_f16(ah[i], bl[j], acc[i][j], 0, 0, 0);
                acc[i][j] = __builtin_amdgcn_mfma_f32_16x16x32_f16(al[i], bh[j], acc[i][j], 0, 0, 0);
            }
    };

    loadfrag(0, a0h, a0l, b0h, b0l);
    for (int kc2 = 0; kc2 < 12; ++kc2) {
        loadfrag(2 * kc2 + 1, a1h, a1l, b1h, b1l);   // prefetch odd tile
        domfma(a0h, a0l, b0h, b0l);                  // compute even tile
        if (kc2 < 11)
            loadfrag(2 * kc2 + 2, a0h, a0l, b0h, b0l); // prefetch next even
        domfma(a1h, a1l, b1h, b1l);                  // compute odd tile
    }

    const float* __restrict__ Worig = which == 0 ? Wq : (which == 1 ? Wk : Wv);
    float* __restrict__ fx = fixs[wave];

    #pragma unroll
    for (int i = 0; i < 4; ++i) {
        #pragma unroll
        for (int j = 0; j < 4; ++j) {
            int n = nb * 128 + wn * 64 + j * 16 + l15;
            int h = n >> 6, d = n & 63;
            float bn = bias[n];
            #pragma unroll
            for (int r = 0; r < 4; ++r) {
                int m = mb * 128 + wm * 64 + i * 16 + g * 4 + r;
                float val = acc[i][j][r] * (1.0f / 65536.0f) + bn;
                if (which < 2) {
                    bool need = fabsf(fabsf(val) - 1.0f) < 1e-4f;
                    unsigned long long msk = __ballot(need);
                    // wave-cooperative recompute for each flagged lane
                    while (msk) {
                        int L = (int)__builtin_ctzll(msk);
                        msk &= msk - 1;
                        // flagged lane's (m,n) derived wave-uniformly from L
                        int Lm = mb * 128 + wm * 64 + i * 16 + (L >> 4) * 4 + r;
                        int Ln = nb * 128 + wn * 64 + j * 16 + (L & 15);
                        // stage X row (coalesced) and W column into LDS
                        #pragma unroll
                        for (int t = 0; t < 12; ++t) {
                            int e = t * 64 + lane;
                            fx[e]       = X[Lm * DM_ + e];
                            fx[768 + e] = Worig[e * DM_ + Ln];
                        }
                        asm volatile("s_waitcnt vmcnt(0) lgkmcnt(0)" ::: "memory");
                        if (lane == L) {
                            // exact R1 sequential fp32 chain (bit-identical values)
                            float a2 = 0.0f;
                            for (int kk = 0; kk < DM_; ++kk)
                                a2 = fmaf(fx[kk], fx[768 + kk], a2);
                            val = a2 + bn;
                        }
                        asm volatile("s_waitcnt lgkmcnt(0)" ::: "memory");
                    }
                }
                if (which == 0)      val = dual_spike(val);
                else if (which == 1) val = 0.5f * dual_spike(val) + 0.5f * val;
                int b = m >> 9, s = m & 511;
                out[(((b * H_ + h) * S_) + s) * D_ + d] = val;
            }
        }
    }
}

// ---------------- Kernel 2: score threshold counts ----------------
__global__ __launch_bounds__(256) void score_sums(
    const float* __restrict__ q, const float* __restrict__ k,
    float* __restrict__ xh, float* __restrict__ xw)
{
    __shared__ __align__(16) float Qt[64][68];
    __shared__ __align__(16) float Kt[64][68];
    __shared__ float colred[16][64];

    const int bh = blockIdx.z;
    const int q0 = blockIdx.y * 64, k0 = blockIdx.x * 64;
    const int tid = threadIdx.x, tx = tid & 15, ty = tid >> 4;
    const float* __restrict__ qb = q + bh * S_ * D_;
    const float* __restrict__ kb = k + bh * S_ * D_;

    #pragma unroll
    for (int t = 0; t < 4; ++t) {
        int e = tid + t * 256;
        int r = e >> 4, c4 = (e & 15) << 2;
        const float4 qv = *reinterpret_cast<const float4*>(&qb[(q0 + r) * D_ + c4]);
        Qt[c4+0][r] = qv.x; Qt[c4+1][r] = qv.y; Qt[c4+2][r] = qv.z; Qt[c4+3][r] = qv.w;
        const float4 kv = *reinterpret_cast<const float4*>(&kb[(k0 + r) * D_ + c4]);
        Kt[c4+0][r] = kv.x; Kt[c4+1][r] = kv.y; Kt[c4+2][r] = kv.z; Kt[c4+3][r] = kv.w;
    }
    __syncthreads();

    float dot[4][4];
    #pragma unroll
    for (int i = 0; i < 4; ++i)
        #pragma unroll
        for (int j = 0; j < 4; ++j) dot[i][j] = 0.0f;

    for (int d = 0; d < 64; ++d) {
        float4 av = *reinterpret_cast<const float4*>(&Qt[d][ty * 4]);
        float4 bv = *reinterpret_cast<const float4*>(&Kt[d][tx * 4]);
        float a[4] = {av.x, av.y, av.z, av.w};
        float b[4] = {bv.x, bv.y, bv.z, bv.w};
        #pragma unroll
        for (int i = 0; i < 4; ++i)
            #pragma unroll
            for (int j = 0; j < 4; ++j)
                dot[i][j] = fmaf(a[i], b[j], dot[i][j]);
    }

    float rowc[4] = {0,0,0,0}, colc[4] = {0,0,0,0};
    #pragma unroll
    for (int i = 0; i < 4; ++i)
        #pragma unroll
        for (int j = 0; j < 4; ++j) {
            float t1 = dot[i][j] >= 8.0f ? 1.0f : 0.0f;
            rowc[i] += t1; colc[j] += t1;
        }
    #pragma unroll
    for (int i = 0; i < 4; ++i) {
        float rsum = rowc[i];
        for (int o = 1; o < 16; o <<= 1) rsum += __shfl_xor(rsum, o, 16);
        if (tx == 0) atomicAdd(&xh[bh * S_ + q0 + ty * 4 + i], rsum);
    }
    #pragma unroll
    for (int j = 0; j < 4; ++j) colred[ty][tx * 4 + j] = colc[j];
    __syncthreads();
    if (tid < 64) {
        float ssum = 0.0f;
        #pragma unroll
        for (int t = 0; t < 16; ++t) ssum += colred[t][tid];
        atomicAdd(&xw[bh * S_ + k0 + tid], ssum);
    }
}

// ---------------- Kernel 3: tiny conv / batchnorm / sigmoid ----------------
__global__ __launch_bounds__(1024) void small_ops(
    const float* __restrict__ xh, const float* __restrict__ xw,
    const float* __restrict__ c1w, const float* __restrict__ gamma,
    const float* __restrict__ beta, const float* __restrict__ chw,
    const float* __restrict__ cww,
    float* __restrict__ y, float* __restrict__ s_h, float* __restrict__ s_w)
{
    const int tid = threadIdx.x;
    __shared__ float red[1024];
    __shared__ float c1s[36], chs[36], cws[36];
    __shared__ float mu_s[3], rs_s[3];
    if (tid < 36) { c1s[tid] = c1w[tid]; chs[tid] = chw[tid]; cws[tid] = cww[tid]; }
    __syncthreads();

    for (int e = tid; e < B_ * 3 * 1024; e += 1024) {
        int n = e & 1023; int br = e >> 10; int r = br % 3; int b = br / 3;
        float acc = 0.0f;
        #pragma unroll
        for (int h = 0; h < 12; ++h) {
            float cv = (n < 512) ? xh[(b * H_ + h) * S_ + n]
                                 : xw[(b * H_ + h) * S_ + (n - 512)];
            acc = fmaf(c1s[r * 12 + h], cv * (1.0f / 512.0f), acc);
        }
        y[e] = acc;
    }
    __syncthreads();

    for (int r = 0; r < 3; ++r) {
        float s = 0.0f;
        for (int e = tid; e < 8192; e += 1024) {
            int b = e >> 10, n = e & 1023;
            s += y[((b * 3 + r) << 10) | n];
        }
        red[tid] = s; __syncthreads();
        for (int o = 512; o > 0; o >>= 1) { if (tid < o) red[tid] += red[tid + o]; __syncthreads(); }
        if (tid == 0) mu_s[r] = red[0] * (1.0f / 8192.0f);
        __syncthreads();
    }
    for (int r = 0; r < 3; ++r) {
        float mu = mu_s[r]; float s = 0.0f;
        for (int e = tid; e < 8192; e += 1024) {
            int b = e >> 10, n = e & 1023;
            float d = y[((b * 3 + r) << 10) | n] - mu;
            s = fmaf(d, d, s);
        }
        red[tid] = s; __syncthreads();
        for (int o = 512; o > 0; o >>= 1) { if (tid < o) red[tid] += red[tid + o]; __syncthreads(); }
        if (tid == 0) rs_s[r] = rsqrtf(red[0] * (1.0f / 8192.0f) + 1e-5f);
        __syncthreads();
    }
    for (int e = tid; e < B_ * H_ * S_; e += 1024) {
        int s = e & 511; int bh = e >> 9; int h = bh % H_; int b = bh / H_;
        float ah = 0.0f, aw = 0.0f;
        #pragma unroll
        for (int r = 0; r < 3; ++r) {
            int yb = (b * 3 + r) << 10;
            float yh = fmaxf((y[yb + s]       - mu_s[r]) * rs_s[r] * gamma[r] + beta[r], 0.0f);
            float yw = fmaxf((y[yb + 512 + s] - mu_s[r]) * rs_s[r] * gamma[r] + beta[r], 0.0f);
            ah = fmaf(chs[h * 3 + r], yh, ah);
            aw = fmaf(cws[h * 3 + r], yw, aw);
        }
        s_h[e] = 1.0f / (1.0f + expf(-ah));
        s_w[e] = 1.0f / (1.0f + expf(-aw));
    }
}

// ---------------- Kernel 4: recompute scores + bias + online softmax + PV ------
__global__ __launch_bounds__(256) void attn_pv(
    const float* __restrict__ q, const float* __restrict__ k,
    const float* __restrict__ v, const float* __restrict__ mask,
    const float* __restrict__ s_h, const float* __restrict__ s_w,
    float* __restrict__ out)
{
    __shared__ __align__(16) float Qt[64][68];
    __shared__ __align__(16) float Kt[64][68];
    __shared__ __align__(16) float Vs[64][68];

    const int bh = blockIdx.y;
    const int b = bh / H_, h = bh % H_;
    const int q0 = blockIdx.x * 64;
    const int tid = threadIdx.x, tx = tid & 15, ty = tid >> 4;
    const float* __restrict__ qb = q + bh * S_ * D_;
    const float* __restrict__ kb = k + bh * S_ * D_;
    const float* __restrict__ vb = v + bh * S_ * D_;

    #pragma unroll
    for (int t = 0; t < 4; ++t) {
        int e = tid + t * 256;
        int r = e >> 4, c4 = (e & 15) << 2;
        const float4 qv = *reinterpret_cast<const float4*>(&qb[(q0 + r) * D_ + c4]);
        Qt[c4+0][r] = qv.x; Qt[c4+1][r] = qv.y; Qt[c4+2][r] = qv.z; Qt[c4+3][r] = qv.w;
    }
    float shq[4];
    #pragma unroll
    for (int i = 0; i < 4; ++i) shq[i] = s_h[bh * S_ + q0 + ty * 4 + i];

    float m_r[4], l_r[4], ctx[4][4];
    #pragma unroll
    for (int i = 0; i < 4; ++i) {
        m_r[i] = -INFINITY; l_r[i] = 0.0f;
        #pragma unroll
        for (int j = 0; j < 4; ++j) ctx[i][j] = 0.0f;
    }

    for (int k0 = 0; k0 < S_; k0 += 64) {
        __syncthreads();
        #pragma unroll
        for (int t = 0; t < 4; ++t) {
            int e = tid + t * 256;
            int r = e >> 4, c4 = (e & 15) << 2;
            const float4 kv = *reinterpret_cast<const float4*>(&kb[(k0 + r) * D_ + c4]);
            Kt[c4+0][r] = kv.x; Kt[c4+1][r] = kv.y; Kt[c4+2][r] = kv.z; Kt[c4+3][r] = kv.w;
            *reinterpret_cast<float4*>(&Vs[r][c4]) =
                *reinterpret_cast<const float4*>(&vb[(k0 + r) * D_ + c4]);
        }
        __syncthreads();

        float dot[4][4];
        #pragma unroll
        for (int i = 0; i < 4; ++i)
            #pragma unroll
            for (int j = 0; j < 4; ++j) dot[i][j] = 0.0f;
        for (int d = 0; d < 64; ++d) {
            float4 av = *reinterpret_cast<const float4*>(&Qt[d][ty * 4]);
            float4 bv = *reinterpret_cast<const float4*>(&Kt[d][tx * 4]);
            float a[4] = {av.x, av.y, av.z, av.w};
            float bb[4] = {bv.x, bv.y, bv.z, bv.w};
            #pragma unroll
            for (int i = 0; i < 4; ++i)
                #pragma unroll
                for (int j = 0; j < 4; ++j)
                    dot[i][j] = fmaf(a[i], bb[j], dot[i][j]);
        }

        float swj[4], mj[4];
        #pragma unroll
        for (int j = 0; j < 4; ++j) {
            swj[j] = s_w[bh * S_ + k0 + tx * 4 + j];
            mj[j]  = mask[b * S_ + k0 + tx * 4 + j];
        }
        float sc[4][4];
        #pragma unroll
        for (int i = 0; i < 4; ++i)
            #pragma unroll
            for (int j = 0; j < 4; ++j) {
                float t1 = dot[i][j] >= 8.0f ? 1.0f : 0.0f;
                sc[i][j] = (dot[i][j] * 0.125f + mj[j]) + t1 * (shq[i] * swj[j]);
            }

        float p[4][4], cscale[4];
        #pragma unroll
        for (int i = 0; i < 4; ++i) {
            float tmax = fmaxf(fmaxf(sc[i][0], sc[i][1]), fmaxf(sc[i][2], sc[i][3]));
            for (int o = 1; o < 16; o <<= 1) tmax = fmaxf(tmax, __shfl_xor(tmax, o, 16));
            float mn = fmaxf(m_r[i], tmax);
            float ps = 0.0f;
            #pragma unroll
            for (int j = 0; j < 4; ++j) { p[i][j] = expf(sc[i][j] - mn); ps += p[i][j]; }
            for (int o = 1; o < 16; o <<= 1) ps += __shfl_xor(ps, o, 16);
            float scale = expf(m_r[i] - mn);
            l_r[i] = l_r[i] * scale + ps;
            m_r[i] = mn;
            cscale[i] = scale;
        }
        __syncthreads();
        #pragma unroll
        for (int i = 0; i < 4; ++i)
            #pragma unroll
            for (int j = 0; j < 4; ++j)
                Kt[ty * 4 + i][tx * 4 + j] = p[i][j];
        __syncthreads();
        #pragma unroll
        for (int i = 0; i < 4; ++i)
            #pragma unroll
            for (int j = 0; j < 4; ++j) ctx[i][j] *= cscale[i];
        for (int kk = 0; kk < 64; ++kk) {
            float4 vv = *reinterpret_cast<const float4*>(&Vs[kk][tx * 4]);
            float pv0 = Kt[ty*4+0][kk], pv1 = Kt[ty*4+1][kk];
            float pv2 = Kt[ty*4+2][kk], pv3 = Kt[ty*4+3][kk];
            ctx[0][0] = fmaf(pv0, vv.x, ctx[0][0]); ctx[0][1] = fmaf(pv0, vv.y, ctx[0][1]);
            ctx[0][2] = fmaf(pv0, vv.z, ctx[0][2]); ctx[0][3] = fmaf(pv0, vv.w, ctx[0][3]);
            ctx[1][0] = fmaf(pv1, vv.x, ctx[1][0]); ctx[1][1] = fmaf(pv1, vv.y, ctx[1][1]);
            ctx[1][2] = fmaf(pv1, vv.z, ctx[1][2]); ctx[1][3] = fmaf(pv1, vv.w, ctx[1][3]);
            ctx[2][0] = fmaf(pv2, vv.x, ctx[2][0]); ctx[2][1] = fmaf(pv2, vv.y, ctx[2][1]);
            ctx[2][2] = fmaf(pv2, vv.z, ctx[2][2]); ctx[2][3] = fmaf(pv2, vv.w, ctx[2][3]);
            ctx[3][0] = fmaf(pv3, vv.x, ctx[3][0]); ctx[3][1] = fmaf(pv3, vv.y, ctx[3][1]);
            ctx[3][2] = fmaf(pv3, vv.z, ctx[3][2]); ctx[3][3] = fmaf(pv3, vv.w, ctx[3][3]);
        }
    }
    #pragma unroll
    for (int i = 0; i < 4; ++i) {
        int s = q0 + ty * 4 + i;
        float inv = 1.0f / l_r[i];
        float4 o;
        o.x = ctx[i][0] * inv; o.y = ctx[i][1] * inv;
        o.z = ctx[i][2] * inv; o.w = ctx[i][3] * inv;
        *reinterpret_cast<float4*>(&out[(b * S_ + s) * DM_ + h * D_ + tx * 4]) = o;
    }
}

extern "C" void kernel_launch(void* const* d_in, const int* in_sizes, int n_in,
                              void* d_out, int out_size, void* d_ws, size_t ws_size,
                              hipStream_t stream) {
    const float* X    = (const float*)d_in[0];
    const float* mask = (const float*)d_in[1];
    const float* Wq   = (const float*)d_in[2];
    const float* bq   = (const float*)d_in[3];
    const float* Wk   = (const float*)d_in[4];
    const float* bk   = (const float*)d_in[5];
    const float* Wv   = (const float*)d_in[6];
    const float* bv   = (const float*)d_in[7];
    const float* c1w  = (const float*)d_in[8];
    const float* gam  = (const float*)d_in[9];
    const float* bet  = (const float*)d_in[10];
    const float* chw  = (const float*)d_in[11];
    const float* cww  = (const float*)d_in[12];
    float* out = (float*)d_out;

    float* ws = (float*)d_ws;
    float* q  = ws;                        // 3145728 f32
    float* k  = q  + 3145728;
    float* v  = k  + 3145728;
    float* xh = v  + 3145728;              // 49152
    float* xw = xh + 49152;
    float* y  = xw + 49152;                // 24576
    float* sh = y  + 24576;
    float* sw = sh + 49152;
    _Float16* Xh  = (_Float16*)(sw + 49152);   // 3145728 halves
    _Float16* Xl  = Xh + 3145728;
    _Float16* Wth = Xl + 3145728;              // 1769472 halves
    _Float16* Wtl = Wth + 1769472;             // total ws ~55.6 MiB

    hipMemsetAsync(xh, 0, 2 * 49152 * sizeof(float), stream);

    prep_x<<<1536, 256, 0, stream>>>(X, Xh, Xl);
    prep_w<<<864, 256, 0, stream>>>(Wq, Wk, Wv, Wth, Wtl);
    qkv_mfma<<<576, 256, 0, stream>>>(Xh, Xl, Wth, Wtl,
        X, Wq, bq, Wk, bk, Wv, bv, q, k, v);
    score_sums<<<dim3(8, 8, 96), 256, 0, stream>>>(q, k, xh, xw);
    small_ops<<<1, 1024, 0, stream>>>(xh, xw, c1w, gam, bet, chw, cww, y, sh, sw);
    attn_pv<<<dim3(8, 96), 256, 0, stream>>>(q, k, v, mask, sh, sw, out);
}

// Round 6
// 288.645 us; speedup vs baseline: 1.3198x; 1.1838x over previous
//
#include <hip/hip_runtime.h>
#include <math.h>

#define B_   8
#define S_   512
#define DM_  768
#define H_   12
#define D_   64
#define BH_  96
#define M_   4096   // B_*S_

typedef _Float16 f16x8 __attribute__((ext_vector_type(8)));
typedef float    f32x4 __attribute__((ext_vector_type(4)));

__device__ __forceinline__ float dual_spike(float x) {
    return x >= 1.0f ? 1.0f : (x <= -1.0f ? -1.0f : 0.0f);
}

__device__ __forceinline__ void gload_lds16(const void* g, void* l) {
    __builtin_amdgcn_global_load_lds(
        (const __attribute__((address_space(1))) unsigned int*)g,
        (__attribute__((address_space(3))) unsigned int*)l, 16, 0, 0);
}

// Shared QK dot chain — MUST be bitwise identical wherever t is derived.
// acc holds 256 * dot (k planes are scaled x256). Threshold: dot>=8 <=> acc>=2048.
__device__ __forceinline__ f32x4 qk_dot(const f16x8* qa, const f16x8* kh, const f16x8* kl) {
    f32x4 acc = (f32x4){0.f, 0.f, 0.f, 0.f};
    acc = __builtin_amdgcn_mfma_f32_16x16x32_f16(qa[0], kh[0], acc, 0, 0, 0);
    acc = __builtin_amdgcn_mfma_f32_16x16x32_f16(qa[0], kl[0], acc, 0, 0, 0);
    acc = __builtin_amdgcn_mfma_f32_16x16x32_f16(qa[1], kh[1], acc, 0, 0, 0);
    acc = __builtin_amdgcn_mfma_f32_16x16x32_f16(qa[1], kl[1], acc, 0, 0, 0);
    return acc;
}

// ---------------- Prepass: X -> fp16 hi/lo planes, fragment-major tile order ----
__global__ __launch_bounds__(256) void prep_x(
    const float* __restrict__ X, _Float16* __restrict__ Xh, _Float16* __restrict__ Xl)
{
    int wid  = blockIdx.x * 4 + (threadIdx.x >> 6);
    int lane = threadIdx.x & 63;
    int fm = wid & 7, kc = (wid >> 3) % 24, mb = wid / 192;
    int row = mb * 128 + fm * 16 + (lane & 15);
    int col = kc * 32 + (lane >> 4) * 8;
    const float4* p = reinterpret_cast<const float4*>(&X[row * DM_ + col]);
    float4 x0 = p[0], x1 = p[1];
    float xs[8] = {x0.x, x0.y, x0.z, x0.w, x1.x, x1.y, x1.z, x1.w};
    f16x8 hi, lo;
    #pragma unroll
    for (int j = 0; j < 8; ++j) {
        float v = xs[j] * 256.0f;
        _Float16 h = (_Float16)v;
        hi[j] = h;
        lo[j] = (_Float16)(v - (float)h);
    }
    size_t out = ((size_t)wid * 64 + lane) * 8;
    *reinterpret_cast<f16x8*>(&Xh[out]) = hi;
    *reinterpret_cast<f16x8*>(&Xl[out]) = lo;
}

// ---------------- Prepass: W (q,k,v) -> transposed fp16 hi/lo planes ------------
__global__ __launch_bounds__(256) void prep_w(
    const float* __restrict__ Wq, const float* __restrict__ Wk, const float* __restrict__ Wv,
    _Float16* __restrict__ Wth, _Float16* __restrict__ Wtl)
{
    int wid  = blockIdx.x * 4 + (threadIdx.x >> 6);
    int lane = threadIdx.x & 63;
    int fn = wid & 7, kc = (wid >> 3) % 24;
    int nb = (wid >> 3) / 24 % 6, which = wid / 1152;
    const float* __restrict__ W = which == 0 ? Wq : (which == 1 ? Wk : Wv);
    int c = lane & 15, g = lane >> 4;
    int ncol = nb * 128 + fn * 16 + c;
    int krow = kc * 32 + g * 8;
    f16x8 hi, lo;
    #pragma unroll
    for (int j = 0; j < 8; ++j) {
        float v = W[(krow + j) * DM_ + ncol] * 256.0f;
        _Float16 h = (_Float16)v;
        hi[j] = h;
        lo[j] = (_Float16)(v - (float)h);
    }
    size_t out = ((size_t)wid * 64 + lane) * 8;
    *reinterpret_cast<f16x8*>(&Wth[out]) = hi;
    *reinterpret_cast<f16x8*>(&Wtl[out]) = lo;
}

// ---------------- Kernel 1: QKV projections via fp16 split MFMA (R5, unchanged) --
__global__ __launch_bounds__(256, 2) void qkv_mfma(
    const _Float16* __restrict__ Xh, const _Float16* __restrict__ Xl,
    const _Float16* __restrict__ Wth, const _Float16* __restrict__ Wtl,
    const float* __restrict__ X,
    const float* __restrict__ Wq, const float* __restrict__ bq,
    const float* __restrict__ Wk, const float* __restrict__ bk,
    const float* __restrict__ Wv, const float* __restrict__ bv,
    float* __restrict__ q, float* __restrict__ k, float* __restrict__ v)
{
    const int orig = blockIdx.x;
    const int wg = (orig & 7) * 72 + (orig >> 3);
    const int which = wg / 192;
    const int rem = wg % 192;
    const int mb = rem / 6, nb = rem % 6;

    const float* __restrict__ bias = which == 0 ? bq : (which == 1 ? bk : bv);
    float* __restrict__ out        = which == 0 ? q  : (which == 1 ? k  : v);

    __shared__ __align__(16) float fixs[4][1536];

    const int tid = threadIdx.x;
    const int wave = tid >> 6, lane = tid & 63;
    const int wm = wave >> 1, wn = wave & 1;
    const int l15 = lane & 15, g = lane >> 4;

    const _Float16* __restrict__ pAh = Xh + (size_t)(mb * 24) * 4096 + wm * 2048 + g * 128 + l15 * 8;
    const _Float16* __restrict__ pAl = Xl + (size_t)(mb * 24) * 4096 + wm * 2048 + g * 128 + l15 * 8;
    const _Float16* __restrict__ pBh = Wth + (size_t)((which * 6 + nb) * 24) * 4096 + wn * 2048 + g * 128 + l15 * 8;
    const _Float16* __restrict__ pBl = Wtl + (size_t)((which * 6 + nb) * 24) * 4096 + wn * 2048 + g * 128 + l15 * 8;

    f32x4 acc[4][4];
    #pragma unroll
    for (int i = 0; i < 4; ++i)
        #pragma unroll
        for (int j = 0; j < 4; ++j) acc[i][j] = (f32x4){0.f, 0.f, 0.f, 0.f};

    f16x8 a0h[4], a0l[4], b0h[4], b0l[4];
    f16x8 a1h[4], a1l[4], b1h[4], b1l[4];

    auto loadfrag = [&](int kc, f16x8 (&ah)[4], f16x8 (&al)[4],
                                f16x8 (&bh)[4], f16x8 (&bl)[4]) {
        const size_t o = (size_t)kc * 4096;
        #pragma unroll
        for (int f = 0; f < 4; ++f) {
            ah[f] = *reinterpret_cast<const f16x8*>(pAh + o + f * 512);
            al[f] = *reinterpret_cast<const f16x8*>(pAl + o + f * 512);
            bh[f] = *reinterpret_cast<const f16x8*>(pBh + o + f * 512);
            bl[f] = *reinterpret_cast<const f16x8*>(pBl + o + f * 512);
        }
    };
    auto domfma = [&](f16x8 (&ah)[4], f16x8 (&al)[4],
                      f16x8 (&bh)[4], f16x8 (&bl)[4]) {
        #pragma unroll
        for (int i = 0; i < 4; ++i)
            #pragma unroll
            for (int j = 0; j < 4; ++j) {
                acc[i][j] = __builtin_amdgcn_mfma_f32_16x16x32_f16(ah[i], bh[j], acc[i][j], 0, 0, 0);
                acc[i][j] = __builtin_amdgcn_mfma_f32_16x16x32_f16(ah[i], bl[j], acc[i][j], 0, 0, 0);
                acc[i][j] = __builtin_amdgcn_mfma_f32_16x16x32_f16(al[i], bh[j], acc[i][j], 0, 0, 0);
            }
    };

    loadfrag(0, a0h, a0l, b0h, b0l);
    for (int kc2 = 0; kc2 < 12; ++kc2) {
        loadfrag(2 * kc2 + 1, a1h, a1l, b1h, b1l);
        domfma(a0h, a0l, b0h, b0l);
        if (kc2 < 11)
            loadfrag(2 * kc2 + 2, a0h, a0l, b0h, b0l);
        domfma(a1h, a1l, b1h, b1l);
    }

    const float* __restrict__ Worig = which == 0 ? Wq : (which == 1 ? Wk : Wv);
    float* __restrict__ fx = fixs[wave];

    #pragma unroll
    for (int i = 0; i < 4; ++i) {
        #pragma unroll
        for (int j = 0; j < 4; ++j) {
            int n = nb * 128 + wn * 64 + j * 16 + l15;
            int h = n >> 6, d = n & 63;
            float bn = bias[n];
            #pragma unroll
            for (int r = 0; r < 4; ++r) {
                int m = mb * 128 + wm * 64 + i * 16 + g * 4 + r;
                float val = acc[i][j][r] * (1.0f / 65536.0f) + bn;
                if (which < 2) {
                    bool need = fabsf(fabsf(val) - 1.0f) < 1e-4f;
                    unsigned long long msk = __ballot(need);
                    while (msk) {
                        int L = (int)__builtin_ctzll(msk);
                        msk &= msk - 1;
                        int Lm = mb * 128 + wm * 64 + i * 16 + (L >> 4) * 4 + r;
                        int Ln = nb * 128 + wn * 64 + j * 16 + (L & 15);
                        #pragma unroll
                        for (int t = 0; t < 12; ++t) {
                            int e = t * 64 + lane;
                            fx[e]       = X[Lm * DM_ + e];
                            fx[768 + e] = Worig[e * DM_ + Ln];
                        }
                        asm volatile("s_waitcnt vmcnt(0) lgkmcnt(0)" ::: "memory");
                        if (lane == L) {
                            float a2 = 0.0f;
                            for (int kk = 0; kk < DM_; ++kk)
                                a2 = fmaf(fx[kk], fx[768 + kk], a2);
                            val = a2 + bn;
                        }
                        asm volatile("s_waitcnt lgkmcnt(0)" ::: "memory");
                    }
                }
                if (which == 0)      val = dual_spike(val);
                else if (which == 1) val = 0.5f * dual_spike(val) + 0.5f * val;
                int b = m >> 9, s = m & 511;
                out[(((b * H_ + h) * S_) + s) * D_ + d] = val;
            }
        }
    }
}

// ---------------- Prepass: q,k -> MFMA fragment arrays -------------------------
// Frag unit (bh, s16, dc): 512 halves, element (s = s16*16 + l15, d = dc*32 + g*8 + j)
// at offset wid*512 + lane*8 + j.  Qf exact ({-1,0,1}); Kf split hi/lo x256.
__global__ __launch_bounds__(256) void prep_qk(
    const float* __restrict__ q, const float* __restrict__ k,
    _Float16* __restrict__ Qf, _Float16* __restrict__ Kfh, _Float16* __restrict__ Kfl)
{
    int wid  = blockIdx.x * 4 + (threadIdx.x >> 6);   // (bh*32 + s16)*2 + dc
    int lane = threadIdx.x & 63;
    int dc = wid & 1, s16 = (wid >> 1) & 31, bh = wid >> 6;
    int l15 = lane & 15, g = lane >> 4;
    int s = s16 * 16 + l15;
    int d0 = dc * 32 + g * 8;
    const float* qp = &q[((size_t)bh * S_ + s) * D_ + d0];
    const float* kp = &k[((size_t)bh * S_ + s) * D_ + d0];
    f16x8 qv, kh, kl;
    #pragma unroll
    for (int j = 0; j < 8; ++j) {
        qv[j] = (_Float16)qp[j];                 // exact: q in {-1,0,1}
        float val = kp[j] * 256.0f;
        _Float16 h = (_Float16)val;
        kh[j] = h;
        kl[j] = (_Float16)(val - (float)h);
    }
    size_t o = (size_t)wid * 512 + lane * 8;
    *reinterpret_cast<f16x8*>(&Qf[o])  = qv;
    *reinterpret_cast<f16x8*>(&Kfh[o]) = kh;
    *reinterpret_cast<f16x8*>(&Kfl[o]) = kl;
}

// ---------------- Kernel 2: score threshold counts via MFMA --------------------
// Block = (bh, qt): 64 q-rows x all 512 k. Wave w handles scol16 in {w, w+4, ...}.
__global__ __launch_bounds__(256) void score_sums(
    const _Float16* __restrict__ Qf, const _Float16* __restrict__ Kfh,
    const _Float16* __restrict__ Kfl,
    float* __restrict__ xh, float* __restrict__ xw)
{
    const int blk = blockIdx.x;
    const int qt = blk & 7, bh = blk >> 3;
    const int tid = threadIdx.x, wave = tid >> 6, lane = tid & 63;
    const int l15 = lane & 15, g = lane >> 4;

    __shared__ float rowred[4][64];

    f16x8 qa[4][2];
    #pragma unroll
    for (int sf = 0; sf < 4; ++sf) {
        const _Float16* qb = Qf + (size_t)((bh * 32 + qt * 4 + sf) * 2) * 512 + lane * 8;
        qa[sf][0] = *reinterpret_cast<const f16x8*>(qb);
        qa[sf][1] = *reinterpret_cast<const f16x8*>(qb + 512);
    }
    float rowc[4][4];
    #pragma unroll
    for (int sf = 0; sf < 4; ++sf)
        #pragma unroll
        for (int r = 0; r < 4; ++r) rowc[sf][r] = 0.0f;

    for (int sc8 = 0; sc8 < 8; ++sc8) {
        int scol16 = sc8 * 4 + wave;
        const _Float16* kbh = Kfh + (size_t)((bh * 32 + scol16) * 2) * 512 + lane * 8;
        const _Float16* kbl = Kfl + (size_t)((bh * 32 + scol16) * 2) * 512 + lane * 8;
        f16x8 kh[2] = {*reinterpret_cast<const f16x8*>(kbh),
                       *reinterpret_cast<const f16x8*>(kbh + 512)};
        f16x8 kl[2] = {*reinterpret_cast<const f16x8*>(kbl),
                       *reinterpret_cast<const f16x8*>(kbl + 512)};
        float csum = 0.0f;
        #pragma unroll
        for (int sf = 0; sf < 4; ++sf) {
            f32x4 acc = qk_dot(qa[sf], kh, kl);
            #pragma unroll
            for (int r = 0; r < 4; ++r) {
                float t1 = acc[r] >= 2048.0f ? 1.0f : 0.0f;   // dot >= 8
                rowc[sf][r] += t1;
                csum += t1;
            }
        }
        csum += __shfl_xor(csum, 16);
        csum += __shfl_xor(csum, 32);
        if (g == 0) atomicAdd(&xw[bh * S_ + scol16 * 16 + l15], csum);
    }
    #pragma unroll
    for (int sf = 0; sf < 4; ++sf)
        #pragma unroll
        for (int r = 0; r < 4; ++r) {
            float sv = rowc[sf][r];
            sv += __shfl_xor(sv, 1); sv += __shfl_xor(sv, 2);
            sv += __shfl_xor(sv, 4); sv += __shfl_xor(sv, 8);
            if (l15 == 0) rowred[wave][sf * 16 + g * 4 + r] = sv;
        }
    __syncthreads();
    if (tid < 64) {
        float sv = rowred[0][tid] + rowred[1][tid] + rowred[2][tid] + rowred[3][tid];
        xh[bh * S_ + qt * 64 + tid] = sv;    // exact count, no atomics needed
    }
}

// ---------------- Kernel 3: tiny conv / batchnorm / sigmoid (unchanged) --------
__global__ __launch_bounds__(1024) void small_ops(
    const float* __restrict__ xh, const float* __restrict__ xw,
    const float* __restrict__ c1w, const float* __restrict__ gamma,
    const float* __restrict__ beta, const float* __restrict__ chw,
    const float* __restrict__ cww,
    float* __restrict__ y, float* __restrict__ s_h, float* __restrict__ s_w)
{
    const int tid = threadIdx.x;
    __shared__ float red[1024];
    __shared__ float c1s[36], chs[36], cws[36];
    __shared__ float mu_s[3], rs_s[3];
    if (tid < 36) { c1s[tid] = c1w[tid]; chs[tid] = chw[tid]; cws[tid] = cww[tid]; }
    __syncthreads();

    for (int e = tid; e < B_ * 3 * 1024; e += 1024) {
        int n = e & 1023; int br = e >> 10; int r = br % 3; int b = br / 3;
        float acc = 0.0f;
        #pragma unroll
        for (int h = 0; h < 12; ++h) {
            float cv = (n < 512) ? xh[(b * H_ + h) * S_ + n]
                                 : xw[(b * H_ + h) * S_ + (n - 512)];
            acc = fmaf(c1s[r * 12 + h], cv * (1.0f / 512.0f), acc);
        }
        y[e] = acc;
    }
    __syncthreads();

    for (int r = 0; r < 3; ++r) {
        float s = 0.0f;
        for (int e = tid; e < 8192; e += 1024) {
            int b = e >> 10, n = e & 1023;
            s += y[((b * 3 + r) << 10) | n];
        }
        red[tid] = s; __syncthreads();
        for (int o = 512; o > 0; o >>= 1) { if (tid < o) red[tid] += red[tid + o]; __syncthreads(); }
        if (tid == 0) mu_s[r] = red[0] * (1.0f / 8192.0f);
        __syncthreads();
    }
    for (int r = 0; r < 3; ++r) {
        float mu = mu_s[r]; float s = 0.0f;
        for (int e = tid; e < 8192; e += 1024) {
            int b = e >> 10, n = e & 1023;
            float d = y[((b * 3 + r) << 10) | n] - mu;
            s = fmaf(d, d, s);
        }
        red[tid] = s; __syncthreads();
        for (int o = 512; o > 0; o >>= 1) { if (tid < o) red[tid] += red[tid + o]; __syncthreads(); }
        if (tid == 0) rs_s[r] = rsqrtf(red[0] * (1.0f / 8192.0f) + 1e-5f);
        __syncthreads();
    }
    for (int e = tid; e < B_ * H_ * S_; e += 1024) {
        int s = e & 511; int bh = e >> 9; int h = bh % H_; int b = bh / H_;
        float ah = 0.0f, aw = 0.0f;
        #pragma unroll
        for (int r = 0; r < 3; ++r) {
            int yb = (b * 3 + r) << 10;
            float yh = fmaxf((y[yb + s]       - mu_s[r]) * rs_s[r] * gamma[r] + beta[r], 0.0f);
            float yw = fmaxf((y[yb + 512 + s] - mu_s[r]) * rs_s[r] * gamma[r] + beta[r], 0.0f);
            ah = fmaf(chs[h * 3 + r], yh, ah);
            aw = fmaf(cws[h * 3 + r], yw, aw);
        }
        s_h[e] = 1.0f / (1.0f + expf(-ah));
        s_w[e] = 1.0f / (1.0f + expf(-aw));
    }
}

// ---------------- Kernel 4: MFMA QK^T + bias + online softmax + VALU PV --------
// Block (bh, qt): wave w owns q-rows [w*16, w*16+16). 2 barriers per k-tile.
__global__ __launch_bounds__(256) void attn_pv(
    const _Float16* __restrict__ Qf, const _Float16* __restrict__ Kfh,
    const _Float16* __restrict__ Kfl, const float* __restrict__ v,
    const float* __restrict__ mask, const float* __restrict__ s_h,
    const float* __restrict__ s_w, float* __restrict__ out)
{
    __shared__ __align__(16) float Vs[4096];            // [kk][64] fp32
    __shared__ __align__(16) _Float16 Kst[2][4096];     // K frag planes for this tile
    __shared__ __align__(16) float P_lds[64][68];

    const int bh = blockIdx.y, b = bh / H_, h = bh % H_;
    const int qt = blockIdx.x, q0 = qt * 64;
    const int tid = threadIdx.x, wave = tid >> 6, lane = tid & 63;
    const int l15 = lane & 15, g = lane >> 4;
    const int rl = wave * 16 + g * 4;                   // + reg -> local q row

    const _Float16* qb = Qf + (size_t)((bh * 32 + qt * 4 + wave) * 2) * 512 + lane * 8;
    f16x8 qa[2] = {*reinterpret_cast<const f16x8*>(qb),
                   *reinterpret_cast<const f16x8*>(qb + 512)};

    float shq[4];
    #pragma unroll
    for (int r = 0; r < 4; ++r) shq[r] = s_h[bh * S_ + q0 + rl + r];

    float m_r[4], l_r[4];
    f32x4 ctx[4];
    #pragma unroll
    for (int r = 0; r < 4; ++r) {
        m_r[r] = -INFINITY; l_r[r] = 0.0f;
        ctx[r] = (f32x4){0.f, 0.f, 0.f, 0.f};
    }

    for (int kt = 0; kt < 8; ++kt) {
        __syncthreads();    // prev tile fully consumed (Vs/Kst free)
        {
            const _Float16* sh_ = Kfh + (size_t)((bh * 32 + kt * 4) * 2) * 512;
            const _Float16* sl_ = Kfl + (size_t)((bh * 32 + kt * 4) * 2) * 512;
            #pragma unroll
            for (int c = 0; c < 2; ++c) {
                int u = (c * 4 + wave) * 512;           // halves
                gload_lds16(&sh_[u + lane * 8], &Kst[0][u]);
                gload_lds16(&sl_[u + lane * 8], &Kst[1][u]);
            }
            const float* vsrc = v + ((size_t)bh * S_ + kt * 64) * D_;
            #pragma unroll
            for (int c = 0; c < 4; ++c) {
                int u = (c * 4 + wave) * 256;           // floats
                gload_lds16(&vsrc[u + lane * 4], &Vs[u]);
            }
        }
        __syncthreads();    // staged data visible

        float sc[4][4];     // [fc][reg]
        #pragma unroll
        for (int fc = 0; fc < 4; ++fc) {
            f16x8 kh[2] = {*reinterpret_cast<const f16x8*>(&Kst[0][(fc * 2 + 0) * 512 + lane * 8]),
                           *reinterpret_cast<const f16x8*>(&Kst[0][(fc * 2 + 1) * 512 + lane * 8])};
            f16x8 kl[2] = {*reinterpret_cast<const f16x8*>(&Kst[1][(fc * 2 + 0) * 512 + lane * 8]),
                           *reinterpret_cast<const f16x8*>(&Kst[1][(fc * 2 + 1) * 512 + lane * 8])};
            f32x4 acc = qk_dot(qa, kh, kl);
            int col = kt * 64 + fc * 16 + l15;
            float mj  = mask[b * S_ + col];
            float swj = s_w[bh * S_ + col];
            #pragma unroll
            for (int r = 0; r < 4; ++r) {
                float t1 = acc[r] >= 2048.0f ? 1.0f : 0.0f;   // same chain as score_sums
                sc[fc][r] = acc[r] * 4.8828125e-4f + mj + t1 * (shq[r] * swj);
            }
        }

        float p[4][4], cscale[4];
        #pragma unroll
        for (int r = 0; r < 4; ++r) {
            float tmax = fmaxf(fmaxf(sc[0][r], sc[1][r]), fmaxf(sc[2][r], sc[3][r]));
            tmax = fmaxf(tmax, __shfl_xor(tmax, 1));
            tmax = fmaxf(tmax, __shfl_xor(tmax, 2));
            tmax = fmaxf(tmax, __shfl_xor(tmax, 4));
            tmax = fmaxf(tmax, __shfl_xor(tmax, 8));
            float mn = fmaxf(m_r[r], tmax);
            float ps = 0.0f;
            #pragma unroll
            for (int fc = 0; fc < 4; ++fc) { p[fc][r] = expf(sc[fc][r] - mn); ps += p[fc][r]; }
            ps += __shfl_xor(ps, 1); ps += __shfl_xor(ps, 2);
            ps += __shfl_xor(ps, 4); ps += __shfl_xor(ps, 8);
            float scale = expf(m_r[r] - mn);
            l_r[r] = l_r[r] * scale + ps;
            m_r[r] = mn;
            cscale[r] = scale;
        }
        // P to LDS: each wave writes & reads only its own 16 rows (no barrier needed)
        #pragma unroll
        for (int fc = 0; fc < 4; ++fc)
            #pragma unroll
            for (int r = 0; r < 4; ++r)
                P_lds[rl + r][fc * 16 + l15] = p[fc][r];

        #pragma unroll
        for (int r = 0; r < 4; ++r) ctx[r] *= cscale[r];

        #pragma unroll
        for (int kk4 = 0; kk4 < 16; ++kk4) {
            f32x4 pr0 = *reinterpret_cast<const f32x4*>(&P_lds[rl + 0][kk4 * 4]);
            f32x4 pr1 = *reinterpret_cast<const f32x4*>(&P_lds[rl + 1][kk4 * 4]);
            f32x4 pr2 = *reinterpret_cast<const f32x4*>(&P_lds[rl + 2][kk4 * 4]);
            f32x4 pr3 = *reinterpret_cast<const f32x4*>(&P_lds[rl + 3][kk4 * 4]);
            f32x4 vv0 = *reinterpret_cast<const f32x4*>(&Vs[(kk4 * 4 + 0) * 64 + l15 * 4]);
            f32x4 vv1 = *reinterpret_cast<const f32x4*>(&Vs[(kk4 * 4 + 1) * 64 + l15 * 4]);
            f32x4 vv2 = *reinterpret_cast<const f32x4*>(&Vs[(kk4 * 4 + 2) * 64 + l15 * 4]);
            f32x4 vv3 = *reinterpret_cast<const f32x4*>(&Vs[(kk4 * 4 + 3) * 64 + l15 * 4]);
            ctx[0] += pr0[0] * vv0; ctx[0] += pr0[1] * vv1; ctx[0] += pr0[2] * vv2; ctx[0] += pr0[3] * vv3;
            ctx[1] += pr1[0] * vv0; ctx[1] += pr1[1] * vv1; ctx[1] += pr1[2] * vv2; ctx[1] += pr1[3] * vv3;
            ctx[2] += pr2[0] * vv0; ctx[2] += pr2[1] * vv1; ctx[2] += pr2[2] * vv2; ctx[2] += pr2[3] * vv3;
            ctx[3] += pr3[0] * vv0; ctx[3] += pr3[1] * vv1; ctx[3] += pr3[2] * vv2; ctx[3] += pr3[3] * vv3;
        }
    }
    #pragma unroll
    for (int r = 0; r < 4; ++r) {
        int s = q0 + rl + r;
        float inv = 1.0f / l_r[r];
        f32x4 o = ctx[r] * inv;
        *reinterpret_cast<f32x4*>(&out[((size_t)b * S_ + s) * DM_ + h * D_ + l15 * 4]) = o;
    }
}

extern "C" void kernel_launch(void* const* d_in, const int* in_sizes, int n_in,
                              void* d_out, int out_size, void* d_ws, size_t ws_size,
                              hipStream_t stream) {
    const float* X    = (const float*)d_in[0];
    const float* mask = (const float*)d_in[1];
    const float* Wq   = (const float*)d_in[2];
    const float* bq   = (const float*)d_in[3];
    const float* Wk   = (const float*)d_in[4];
    const float* bk   = (const float*)d_in[5];
    const float* Wv   = (const float*)d_in[6];
    const float* bv   = (const float*)d_in[7];
    const float* c1w  = (const float*)d_in[8];
    const float* gam  = (const float*)d_in[9];
    const float* bet  = (const float*)d_in[10];
    const float* chw  = (const float*)d_in[11];
    const float* cww  = (const float*)d_in[12];
    float* out = (float*)d_out;

    float* ws = (float*)d_ws;
    float* q  = ws;                        // 3145728 f32
    float* k  = q  + 3145728;
    float* v  = k  + 3145728;
    float* xh = v  + 3145728;              // 49152
    float* xw = xh + 49152;
    float* y  = xw + 49152;                // 24576
    float* sh = y  + 24576;
    float* sw = sh + 49152;
    _Float16* Xh  = (_Float16*)(sw + 49152);   // 3145728 halves
    _Float16* Xl  = Xh + 3145728;
    _Float16* Wth = Xl + 3145728;              // 1769472 halves
    _Float16* Wtl = Wth + 1769472;             // total ws ~55.6 MiB

    // Fragment arrays for score/attn overlay the (dead-after-qkv) staging planes:
    _Float16* Qf  = Xh;                        // 3145728 halves
    _Float16* Kfh = Xl;                        // 3145728 halves
    _Float16* Kfl = Wth;                       // 3145728 halves (spans Wth+Wtl)

    hipMemsetAsync(xw, 0, 49152 * sizeof(float), stream);

    prep_x<<<1536, 256, 0, stream>>>(X, Xh, Xl);
    prep_w<<<864, 256, 0, stream>>>(Wq, Wk, Wv, Wth, Wtl);
    qkv_mfma<<<576, 256, 0, stream>>>(Xh, Xl, Wth, Wtl,
        X, Wq, bq, Wk, bk, Wv, bv, q, k, v);
    prep_qk<<<1536, 256, 0, stream>>>(q, k, Qf, Kfh, Kfl);
    score_sums<<<768, 256, 0, stream>>>(Qf, Kfh, Kfl, xh, xw);
    small_ops<<<1, 1024, 0, stream>>>(xh, xw, c1w, gam, bet, chw, cww, y, sh, sw);
    attn_pv<<<dim3(8, BH_), 256, 0, stream>>>(Qf, Kfh, Kfl, v, mask, sh, sw, out);
}

// Round 7
// 275.448 us; speedup vs baseline: 1.3831x; 1.0479x over previous
//
#include <hip/hip_runtime.h>
#include <math.h>

#define B_   8
#define S_   512
#define DM_  768
#define H_   12
#define D_   64
#define BH_  96
#define M_   4096   // B_*S_

typedef _Float16 f16x8 __attribute__((ext_vector_type(8)));
typedef float    f32x4 __attribute__((ext_vector_type(4)));

__device__ __forceinline__ float dual_spike(float x) {
    return x >= 1.0f ? 1.0f : (x <= -1.0f ? -1.0f : 0.0f);
}

__device__ __forceinline__ void gload_lds16(const void* g, void* l) {
    __builtin_amdgcn_global_load_lds(
        (const __attribute__((address_space(1))) unsigned int*)g,
        (__attribute__((address_space(3))) unsigned int*)l, 16, 0, 0);
}

// Shared QK dot chain — MUST be bitwise identical wherever t is derived.
// acc holds 256 * dot (k planes are scaled x256). Threshold: dot>=8 <=> acc>=2048.
__device__ __forceinline__ f32x4 qk_dot(const f16x8* qa, const f16x8* kh, const f16x8* kl) {
    f32x4 acc = (f32x4){0.f, 0.f, 0.f, 0.f};
    acc = __builtin_amdgcn_mfma_f32_16x16x32_f16(qa[0], kh[0], acc, 0, 0, 0);
    acc = __builtin_amdgcn_mfma_f32_16x16x32_f16(qa[0], kl[0], acc, 0, 0, 0);
    acc = __builtin_amdgcn_mfma_f32_16x16x32_f16(qa[1], kh[1], acc, 0, 0, 0);
    acc = __builtin_amdgcn_mfma_f32_16x16x32_f16(qa[1], kl[1], acc, 0, 0, 0);
    return acc;
}

// ---------------- Prepass: X -> fp16 hi/lo planes, fragment-major tile order ----
__global__ __launch_bounds__(256) void prep_x(
    const float* __restrict__ X, _Float16* __restrict__ Xh, _Float16* __restrict__ Xl)
{
    int wid  = blockIdx.x * 4 + (threadIdx.x >> 6);
    int lane = threadIdx.x & 63;
    int fm = wid & 7, kc = (wid >> 3) % 24, mb = wid / 192;
    int row = mb * 128 + fm * 16 + (lane & 15);
    int col = kc * 32 + (lane >> 4) * 8;
    const float4* p = reinterpret_cast<const float4*>(&X[row * DM_ + col]);
    float4 x0 = p[0], x1 = p[1];
    float xs[8] = {x0.x, x0.y, x0.z, x0.w, x1.x, x1.y, x1.z, x1.w};
    f16x8 hi, lo;
    #pragma unroll
    for (int j = 0; j < 8; ++j) {
        float v = xs[j] * 256.0f;
        _Float16 h = (_Float16)v;
        hi[j] = h;
        lo[j] = (_Float16)(v - (float)h);
    }
    size_t out = ((size_t)wid * 64 + lane) * 8;
    *reinterpret_cast<f16x8*>(&Xh[out]) = hi;
    *reinterpret_cast<f16x8*>(&Xl[out]) = lo;
}

// ---------------- Prepass: W (q,k,v) -> transposed fp16 hi/lo planes ------------
__global__ __launch_bounds__(256) void prep_w(
    const float* __restrict__ Wq, const float* __restrict__ Wk, const float* __restrict__ Wv,
    _Float16* __restrict__ Wth, _Float16* __restrict__ Wtl)
{
    int wid  = blockIdx.x * 4 + (threadIdx.x >> 6);
    int lane = threadIdx.x & 63;
    int fn = wid & 7, kc = (wid >> 3) % 24;
    int nb = (wid >> 3) / 24 % 6, which = wid / 1152;
    const float* __restrict__ W = which == 0 ? Wq : (which == 1 ? Wk : Wv);
    int c = lane & 15, g = lane >> 4;
    int ncol = nb * 128 + fn * 16 + c;
    int krow = kc * 32 + g * 8;
    f16x8 hi, lo;
    #pragma unroll
    for (int j = 0; j < 8; ++j) {
        float v = W[(krow + j) * DM_ + ncol] * 256.0f;
        _Float16 h = (_Float16)v;
        hi[j] = h;
        lo[j] = (_Float16)(v - (float)h);
    }
    size_t out = ((size_t)wid * 64 + lane) * 8;
    *reinterpret_cast<f16x8*>(&Wth[out]) = hi;
    *reinterpret_cast<f16x8*>(&Wtl[out]) = lo;
}

// ---------------- Kernel 1: QKV projections via fp16 split MFMA ----------------
// v6: register dbuf ENFORCED via sched_barrier(0) after each load block (defeats
// hipcc load-sinking that collapsed the pipeline — evidence: VGPR_Count 88 in R6).
__global__ __launch_bounds__(256, 2) void qkv_mfma(
    const _Float16* __restrict__ Xh, const _Float16* __restrict__ Xl,
    const _Float16* __restrict__ Wth, const _Float16* __restrict__ Wtl,
    const float* __restrict__ X,
    const float* __restrict__ Wq, const float* __restrict__ bq,
    const float* __restrict__ Wk, const float* __restrict__ bk,
    const float* __restrict__ Wv, const float* __restrict__ bv,
    float* __restrict__ q, float* __restrict__ k, float* __restrict__ v)
{
    const int orig = blockIdx.x;
    const int wg = (orig & 7) * 72 + (orig >> 3);
    const int which = wg / 192;
    const int rem = wg % 192;
    const int mb = rem / 6, nb = rem % 6;

    const float* __restrict__ bias = which == 0 ? bq : (which == 1 ? bk : bv);
    float* __restrict__ out        = which == 0 ? q  : (which == 1 ? k  : v);

    __shared__ __align__(16) float fixs[4][1536];

    const int tid = threadIdx.x;
    const int wave = tid >> 6, lane = tid & 63;
    const int wm = wave >> 1, wn = wave & 1;
    const int l15 = lane & 15, g = lane >> 4;

    const _Float16* __restrict__ pAh = Xh + (size_t)(mb * 24) * 4096 + wm * 2048 + g * 128 + l15 * 8;
    const _Float16* __restrict__ pAl = Xl + (size_t)(mb * 24) * 4096 + wm * 2048 + g * 128 + l15 * 8;
    const _Float16* __restrict__ pBh = Wth + (size_t)((which * 6 + nb) * 24) * 4096 + wn * 2048 + g * 128 + l15 * 8;
    const _Float16* __restrict__ pBl = Wtl + (size_t)((which * 6 + nb) * 24) * 4096 + wn * 2048 + g * 128 + l15 * 8;

    f32x4 acc[4][4];
    #pragma unroll
    for (int i = 0; i < 4; ++i)
        #pragma unroll
        for (int j = 0; j < 4; ++j) acc[i][j] = (f32x4){0.f, 0.f, 0.f, 0.f};

    f16x8 a0h[4], a0l[4], b0h[4], b0l[4];
    f16x8 a1h[4], a1l[4], b1h[4], b1l[4];

    auto loadfrag = [&](int kc, f16x8 (&ah)[4], f16x8 (&al)[4],
                                f16x8 (&bh)[4], f16x8 (&bl)[4]) {
        const size_t o = (size_t)kc * 4096;
        #pragma unroll
        for (int f = 0; f < 4; ++f) {
            ah[f] = *reinterpret_cast<const f16x8*>(pAh + o + f * 512);
            al[f] = *reinterpret_cast<const f16x8*>(pAl + o + f * 512);
            bh[f] = *reinterpret_cast<const f16x8*>(pBh + o + f * 512);
            bl[f] = *reinterpret_cast<const f16x8*>(pBl + o + f * 512);
        }
    };
    auto domfma = [&](f16x8 (&ah)[4], f16x8 (&al)[4],
                      f16x8 (&bh)[4], f16x8 (&bl)[4]) {
        #pragma unroll
        for (int i = 0; i < 4; ++i)
            #pragma unroll
            for (int j = 0; j < 4; ++j) {
                acc[i][j] = __builtin_amdgcn_mfma_f32_16x16x32_f16(ah[i], bh[j], acc[i][j], 0, 0, 0);
                acc[i][j] = __builtin_amdgcn_mfma_f32_16x16x32_f16(ah[i], bl[j], acc[i][j], 0, 0, 0);
                acc[i][j] = __builtin_amdgcn_mfma_f32_16x16x32_f16(al[i], bh[j], acc[i][j], 0, 0, 0);
            }
    };

    loadfrag(0, a0h, a0l, b0h, b0l);
    __builtin_amdgcn_sched_barrier(0);   // pin: buf0 loads issued before anything below
    for (int kc2 = 0; kc2 < 12; ++kc2) {
        loadfrag(2 * kc2 + 1, a1h, a1l, b1h, b1l);   // prefetch odd tile
        __builtin_amdgcn_sched_barrier(0);           // loads stay ABOVE the MFMAs
        domfma(a0h, a0l, b0h, b0l);                  // compute even tile
        __builtin_amdgcn_sched_barrier(0);
        if (kc2 < 11) {
            loadfrag(2 * kc2 + 2, a0h, a0l, b0h, b0l); // prefetch next even
        }
        __builtin_amdgcn_sched_barrier(0);
        domfma(a1h, a1l, b1h, b1l);                  // compute odd tile
        __builtin_amdgcn_sched_barrier(0);
    }

    const float* __restrict__ Worig = which == 0 ? Wq : (which == 1 ? Wk : Wv);
    float* __restrict__ fx = fixs[wave];

    #pragma unroll
    for (int i = 0; i < 4; ++i) {
        #pragma unroll
        for (int j = 0; j < 4; ++j) {
            int n = nb * 128 + wn * 64 + j * 16 + l15;
            int h = n >> 6, d = n & 63;
            float bn = bias[n];
            #pragma unroll
            for (int r = 0; r < 4; ++r) {
                int m = mb * 128 + wm * 64 + i * 16 + g * 4 + r;
                float val = acc[i][j][r] * (1.0f / 65536.0f) + bn;
                if (which < 2) {
                    bool need = fabsf(fabsf(val) - 1.0f) < 1e-4f;
                    unsigned long long msk = __ballot(need);
                    while (msk) {
                        int L = (int)__builtin_ctzll(msk);
                        msk &= msk - 1;
                        int Lm = mb * 128 + wm * 64 + i * 16 + (L >> 4) * 4 + r;
                        int Ln = nb * 128 + wn * 64 + j * 16 + (L & 15);
                        #pragma unroll
                        for (int t = 0; t < 12; ++t) {
                            int e = t * 64 + lane;
                            fx[e]       = X[Lm * DM_ + e];
                            fx[768 + e] = Worig[e * DM_ + Ln];
                        }
                        asm volatile("s_waitcnt vmcnt(0) lgkmcnt(0)" ::: "memory");
                        if (lane == L) {
                            float a2 = 0.0f;
                            for (int kk = 0; kk < DM_; ++kk)
                                a2 = fmaf(fx[kk], fx[768 + kk], a2);
                            val = a2 + bn;
                        }
                        asm volatile("s_waitcnt lgkmcnt(0)" ::: "memory");
                    }
                }
                if (which == 0)      val = dual_spike(val);
                else if (which == 1) val = 0.5f * dual_spike(val) + 0.5f * val;
                int b = m >> 9, s = m & 511;
                out[(((b * H_ + h) * S_) + s) * D_ + d] = val;
            }
        }
    }
}

// ---------------- Prepass: q,k -> MFMA fragment arrays -------------------------
__global__ __launch_bounds__(256) void prep_qk(
    const float* __restrict__ q, const float* __restrict__ k,
    _Float16* __restrict__ Qf, _Float16* __restrict__ Kfh, _Float16* __restrict__ Kfl)
{
    int wid  = blockIdx.x * 4 + (threadIdx.x >> 6);   // (bh*32 + s16)*2 + dc
    int lane = threadIdx.x & 63;
    int dc = wid & 1, s16 = (wid >> 1) & 31, bh = wid >> 6;
    int l15 = lane & 15, g = lane >> 4;
    int s = s16 * 16 + l15;
    int d0 = dc * 32 + g * 8;
    const float* qp = &q[((size_t)bh * S_ + s) * D_ + d0];
    const float* kp = &k[((size_t)bh * S_ + s) * D_ + d0];
    f16x8 qv, kh, kl;
    #pragma unroll
    for (int j = 0; j < 8; ++j) {
        qv[j] = (_Float16)qp[j];                 // exact: q in {-1,0,1}
        float val = kp[j] * 256.0f;
        _Float16 h = (_Float16)val;
        kh[j] = h;
        kl[j] = (_Float16)(val - (float)h);
    }
    size_t o = (size_t)wid * 512 + lane * 8;
    *reinterpret_cast<f16x8*>(&Qf[o])  = qv;
    *reinterpret_cast<f16x8*>(&Kfh[o]) = kh;
    *reinterpret_cast<f16x8*>(&Kfl[o]) = kl;
}

// ---------------- Kernel 2: score threshold counts via MFMA --------------------
__global__ __launch_bounds__(256) void score_sums(
    const _Float16* __restrict__ Qf, const _Float16* __restrict__ Kfh,
    const _Float16* __restrict__ Kfl,
    float* __restrict__ xh, float* __restrict__ xw)
{
    const int blk = blockIdx.x;
    const int qt = blk & 7, bh = blk >> 3;
    const int tid = threadIdx.x, wave = tid >> 6, lane = tid & 63;
    const int l15 = lane & 15, g = lane >> 4;

    __shared__ float rowred[4][64];

    f16x8 qa[4][2];
    #pragma unroll
    for (int sf = 0; sf < 4; ++sf) {
        const _Float16* qb = Qf + (size_t)((bh * 32 + qt * 4 + sf) * 2) * 512 + lane * 8;
        qa[sf][0] = *reinterpret_cast<const f16x8*>(qb);
        qa[sf][1] = *reinterpret_cast<const f16x8*>(qb + 512);
    }
    float rowc[4][4];
    #pragma unroll
    for (int sf = 0; sf < 4; ++sf)
        #pragma unroll
        for (int r = 0; r < 4; ++r) rowc[sf][r] = 0.0f;

    for (int sc8 = 0; sc8 < 8; ++sc8) {
        int scol16 = sc8 * 4 + wave;
        const _Float16* kbh = Kfh + (size_t)((bh * 32 + scol16) * 2) * 512 + lane * 8;
        const _Float16* kbl = Kfl + (size_t)((bh * 32 + scol16) * 2) * 512 + lane * 8;
        f16x8 kh[2] = {*reinterpret_cast<const f16x8*>(kbh),
                       *reinterpret_cast<const f16x8*>(kbh + 512)};
        f16x8 kl[2] = {*reinterpret_cast<const f16x8*>(kbl),
                       *reinterpret_cast<const f16x8*>(kbl + 512)};
        float csum = 0.0f;
        #pragma unroll
        for (int sf = 0; sf < 4; ++sf) {
            f32x4 acc = qk_dot(qa[sf], kh, kl);
            #pragma unroll
            for (int r = 0; r < 4; ++r) {
                float t1 = acc[r] >= 2048.0f ? 1.0f : 0.0f;   // dot >= 8
                rowc[sf][r] += t1;
                csum += t1;
            }
        }
        csum += __shfl_xor(csum, 16);
        csum += __shfl_xor(csum, 32);
        if (g == 0) atomicAdd(&xw[bh * S_ + scol16 * 16 + l15], csum);
    }
    #pragma unroll
    for (int sf = 0; sf < 4; ++sf)
        #pragma unroll
        for (int r = 0; r < 4; ++r) {
            float sv = rowc[sf][r];
            sv += __shfl_xor(sv, 1); sv += __shfl_xor(sv, 2);
            sv += __shfl_xor(sv, 4); sv += __shfl_xor(sv, 8);
            if (l15 == 0) rowred[wave][sf * 16 + g * 4 + r] = sv;
        }
    __syncthreads();
    if (tid < 64) {
        float sv = rowred[0][tid] + rowred[1][tid] + rowred[2][tid] + rowred[3][tid];
        xh[bh * S_ + qt * 64 + tid] = sv;    // exact count, no atomics needed
    }
}

// ---------------- Kernel 3: tiny conv / batchnorm / sigmoid (unchanged) --------
__global__ __launch_bounds__(1024) void small_ops(
    const float* __restrict__ xh, const float* __restrict__ xw,
    const float* __restrict__ c1w, const float* __restrict__ gamma,
    const float* __restrict__ beta, const float* __restrict__ chw,
    const float* __restrict__ cww,
    float* __restrict__ y, float* __restrict__ s_h, float* __restrict__ s_w)
{
    const int tid = threadIdx.x;
    __shared__ float red[1024];
    __shared__ float c1s[36], chs[36], cws[36];
    __shared__ float mu_s[3], rs_s[3];
    if (tid < 36) { c1s[tid] = c1w[tid]; chs[tid] = chw[tid]; cws[tid] = cww[tid]; }
    __syncthreads();

    for (int e = tid; e < B_ * 3 * 1024; e += 1024) {
        int n = e & 1023; int br = e >> 10; int r = br % 3; int b = br / 3;
        float acc = 0.0f;
        #pragma unroll
        for (int h = 0; h < 12; ++h) {
            float cv = (n < 512) ? xh[(b * H_ + h) * S_ + n]
                                 : xw[(b * H_ + h) * S_ + (n - 512)];
            acc = fmaf(c1s[r * 12 + h], cv * (1.0f / 512.0f), acc);
        }
        y[e] = acc;
    }
    __syncthreads();

    for (int r = 0; r < 3; ++r) {
        float s = 0.0f;
        for (int e = tid; e < 8192; e += 1024) {
            int b = e >> 10, n = e & 1023;
            s += y[((b * 3 + r) << 10) | n];
        }
        red[tid] = s; __syncthreads();
        for (int o = 512; o > 0; o >>= 1) { if (tid < o) red[tid] += red[tid + o]; __syncthreads(); }
        if (tid == 0) mu_s[r] = red[0] * (1.0f / 8192.0f);
        __syncthreads();
    }
    for (int r = 0; r < 3; ++r) {
        float mu = mu_s[r]; float s = 0.0f;
        for (int e = tid; e < 8192; e += 1024) {
            int b = e >> 10, n = e & 1023;
            float d = y[((b * 3 + r) << 10) | n] - mu;
            s = fmaf(d, d, s);
        }
        red[tid] = s; __syncthreads();
        for (int o = 512; o > 0; o >>= 1) { if (tid < o) red[tid] += red[tid + o]; __syncthreads(); }
        if (tid == 0) rs_s[r] = rsqrtf(red[0] * (1.0f / 8192.0f) + 1e-5f);
        __syncthreads();
    }
    for (int e = tid; e < B_ * H_ * S_; e += 1024) {
        int s = e & 511; int bh = e >> 9; int h = bh % H_; int b = bh / H_;
        float ah = 0.0f, aw = 0.0f;
        #pragma unroll
        for (int r = 0; r < 3; ++r) {
            int yb = (b * 3 + r) << 10;
            float yh = fmaxf((y[yb + s]       - mu_s[r]) * rs_s[r] * gamma[r] + beta[r], 0.0f);
            float yw = fmaxf((y[yb + 512 + s] - mu_s[r]) * rs_s[r] * gamma[r] + beta[r], 0.0f);
            ah = fmaf(chs[h * 3 + r], yh, ah);
            aw = fmaf(cws[h * 3 + r], yw, aw);
        }
        s_h[e] = 1.0f / (1.0f + expf(-ah));
        s_w[e] = 1.0f / (1.0f + expf(-aw));
    }
}

// ---------------- Kernel 4: MFMA QK^T + bias + online softmax + VALU PV --------
__global__ __launch_bounds__(256) void attn_pv(
    const _Float16* __restrict__ Qf, const _Float16* __restrict__ Kfh,
    const _Float16* __restrict__ Kfl, const float* __restrict__ v,
    const float* __restrict__ mask, const float* __restrict__ s_h,
    const float* __restrict__ s_w, float* __restrict__ out)
{
    __shared__ __align__(16) float Vs[4096];            // [kk][64] fp32
    __shared__ __align__(16) _Float16 Kst[2][4096];     // K frag planes for this tile
    __shared__ __align__(16) float P_lds[64][68];

    const int bh = blockIdx.y, b = bh / H_, h = bh % H_;
    const int qt = blockIdx.x, q0 = qt * 64;
    const int tid = threadIdx.x, wave = tid >> 6, lane = tid & 63;
    const int l15 = lane & 15, g = lane >> 4;
    const int rl = wave * 16 + g * 4;                   // + reg -> local q row

    const _Float16* qb = Qf + (size_t)((bh * 32 + qt * 4 + wave) * 2) * 512 + lane * 8;
    f16x8 qa[2] = {*reinterpret_cast<const f16x8*>(qb),
                   *reinterpret_cast<const f16x8*>(qb + 512)};

    float shq[4];
    #pragma unroll
    for (int r = 0; r < 4; ++r) shq[r] = s_h[bh * S_ + q0 + rl + r];

    float m_r[4], l_r[4];
    f32x4 ctx[4];
    #pragma unroll
    for (int r = 0; r < 4; ++r) {
        m_r[r] = -INFINITY; l_r[r] = 0.0f;
        ctx[r] = (f32x4){0.f, 0.f, 0.f, 0.f};
    }

    for (int kt = 0; kt < 8; ++kt) {
        __syncthreads();    // prev tile fully consumed (Vs/Kst free)
        {
            const _Float16* sh_ = Kfh + (size_t)((bh * 32 + kt * 4) * 2) * 512;
            const _Float16* sl_ = Kfl + (size_t)((bh * 32 + kt * 4) * 2) * 512;
            #pragma unroll
            for (int c = 0; c < 2; ++c) {
                int u = (c * 4 + wave) * 512;           // halves
                gload_lds16(&sh_[u + lane * 8], &Kst[0][u]);
                gload_lds16(&sl_[u + lane * 8], &Kst[1][u]);
            }
            const float* vsrc = v + ((size_t)bh * S_ + kt * 64) * D_;
            #pragma unroll
            for (int c = 0; c < 4; ++c) {
                int u = (c * 4 + wave) * 256;           // floats
                gload_lds16(&vsrc[u + lane * 4], &Vs[u]);
            }
        }
        __syncthreads();    // staged data visible

        float sc[4][4];     // [fc][reg]
        #pragma unroll
        for (int fc = 0; fc < 4; ++fc) {
            f16x8 kh[2] = {*reinterpret_cast<const f16x8*>(&Kst[0][(fc * 2 + 0) * 512 + lane * 8]),
                           *reinterpret_cast<const f16x8*>(&Kst[0][(fc * 2 + 1) * 512 + lane * 8])};
            f16x8 kl[2] = {*reinterpret_cast<const f16x8*>(&Kst[1][(fc * 2 + 0) * 512 + lane * 8]),
                           *reinterpret_cast<const f16x8*>(&Kst[1][(fc * 2 + 1) * 512 + lane * 8])};
            f32x4 acc = qk_dot(qa, kh, kl);
            int col = kt * 64 + fc * 16 + l15;
            float mj  = mask[b * S_ + col];
            float swj = s_w[bh * S_ + col];
            #pragma unroll
            for (int r = 0; r < 4; ++r) {
                float t1 = acc[r] >= 2048.0f ? 1.0f : 0.0f;   // same chain as score_sums
                sc[fc][r] = acc[r] * 4.8828125e-4f + mj + t1 * (shq[r] * swj);
            }
        }

        float p[4][4], cscale[4];
        #pragma unroll
        for (int r = 0; r < 4; ++r) {
            float tmax = fmaxf(fmaxf(sc[0][r], sc[1][r]), fmaxf(sc[2][r], sc[3][r]));
            tmax = fmaxf(tmax, __shfl_xor(tmax, 1));
            tmax = fmaxf(tmax, __shfl_xor(tmax, 2));
            tmax = fmaxf(tmax, __shfl_xor(tmax, 4));
            tmax = fmaxf(tmax, __shfl_xor(tmax, 8));
            float mn = fmaxf(m_r[r], tmax);
            float ps = 0.0f;
            #pragma unroll
            for (int fc = 0; fc < 4; ++fc) { p[fc][r] = expf(sc[fc][r] - mn); ps += p[fc][r]; }
            ps += __shfl_xor(ps, 1); ps += __shfl_xor(ps, 2);
            ps += __shfl_xor(ps, 4); ps += __shfl_xor(ps, 8);
            float scale = expf(m_r[r] - mn);
            l_r[r] = l_r[r] * scale + ps;
            m_r[r] = mn;
            cscale[r] = scale;
        }
        // P to LDS: each wave writes & reads only its own 16 rows (no barrier needed)
        #pragma unroll
        for (int fc = 0; fc < 4; ++fc)
            #pragma unroll
            for (int r = 0; r < 4; ++r)
                P_lds[rl + r][fc * 16 + l15] = p[fc][r];

        #pragma unroll
        for (int r = 0; r < 4; ++r) ctx[r] *= cscale[r];

        #pragma unroll
        for (int kk4 = 0; kk4 < 16; ++kk4) {
            f32x4 pr0 = *reinterpret_cast<const f32x4*>(&P_lds[rl + 0][kk4 * 4]);
            f32x4 pr1 = *reinterpret_cast<const f32x4*>(&P_lds[rl + 1][kk4 * 4]);
            f32x4 pr2 = *reinterpret_cast<const f32x4*>(&P_lds[rl + 2][kk4 * 4]);
            f32x4 pr3 = *reinterpret_cast<const f32x4*>(&P_lds[rl + 3][kk4 * 4]);
            f32x4 vv0 = *reinterpret_cast<const f32x4*>(&Vs[(kk4 * 4 + 0) * 64 + l15 * 4]);
            f32x4 vv1 = *reinterpret_cast<const f32x4*>(&Vs[(kk4 * 4 + 1) * 64 + l15 * 4]);
            f32x4 vv2 = *reinterpret_cast<const f32x4*>(&Vs[(kk4 * 4 + 2) * 64 + l15 * 4]);
            f32x4 vv3 = *reinterpret_cast<const f32x4*>(&Vs[(kk4 * 4 + 3) * 64 + l15 * 4]);
            ctx[0] += pr0[0] * vv0; ctx[0] += pr0[1] * vv1; ctx[0] += pr0[2] * vv2; ctx[0] += pr0[3] * vv3;
            ctx[1] += pr1[0] * vv0; ctx[1] += pr1[1] * vv1; ctx[1] += pr1[2] * vv2; ctx[1] += pr1[3] * vv3;
            ctx[2] += pr2[0] * vv0; ctx[2] += pr2[1] * vv1; ctx[2] += pr2[2] * vv2; ctx[2] += pr2[3] * vv3;
            ctx[3] += pr3[0] * vv0; ctx[3] += pr3[1] * vv1; ctx[3] += pr3[2] * vv2; ctx[3] += pr3[3] * vv3;
        }
    }
    #pragma unroll
    for (int r = 0; r < 4; ++r) {
        int s = q0 + rl + r;
        float inv = 1.0f / l_r[r];
        f32x4 o = ctx[r] * inv;
        *reinterpret_cast<f32x4*>(&out[((size_t)b * S_ + s) * DM_ + h * D_ + l15 * 4]) = o;
    }
}

extern "C" void kernel_launch(void* const* d_in, const int* in_sizes, int n_in,
                              void* d_out, int out_size, void* d_ws, size_t ws_size,
                              hipStream_t stream) {
    const float* X    = (const float*)d_in[0];
    const float* mask = (const float*)d_in[1];
    const float* Wq   = (const float*)d_in[2];
    const float* bq   = (const float*)d_in[3];
    const float* Wk   = (const float*)d_in[4];
    const float* bk   = (const float*)d_in[5];
    const float* Wv   = (const float*)d_in[6];
    const float* bv   = (const float*)d_in[7];
    const float* c1w  = (const float*)d_in[8];
    const float* gam  = (const float*)d_in[9];
    const float* bet  = (const float*)d_in[10];
    const float* chw  = (const float*)d_in[11];
    const float* cww  = (const float*)d_in[12];
    float* out = (float*)d_out;

    float* ws = (float*)d_ws;
    float* q  = ws;                        // 3145728 f32
    float* k  = q  + 3145728;
    float* v  = k  + 3145728;
    float* xh = v  + 3145728;              // 49152
    float* xw = xh + 49152;
    float* y  = xw + 49152;                // 24576
    float* sh = y  + 24576;
    float* sw = sh + 49152;
    _Float16* Xh  = (_Float16*)(sw + 49152);   // 3145728 halves
    _Float16* Xl  = Xh + 3145728;
    _Float16* Wth = Xl + 3145728;              // 1769472 halves
    _Float16* Wtl = Wth + 1769472;             // total ws ~55.6 MiB

    // Fragment arrays for score/attn overlay the (dead-after-qkv) staging planes:
    _Float16* Qf  = Xh;                        // 3145728 halves
    _Float16* Kfh = Xl;                        // 3145728 halves
    _Float16* Kfl = Wth;                       // 3145728 halves (spans Wth+Wtl)

    hipMemsetAsync(xw, 0, 49152 * sizeof(float), stream);

    prep_x<<<1536, 256, 0, stream>>>(X, Xh, Xl);
    prep_w<<<864, 256, 0, stream>>>(Wq, Wk, Wv, Wth, Wtl);
    qkv_mfma<<<576, 256, 0, stream>>>(Xh, Xl, Wth, Wtl,
        X, Wq, bq, Wk, bk, Wv, bv, q, k, v);
    prep_qk<<<1536, 256, 0, stream>>>(q, k, Qf, Kfh, Kfl);
    score_sums<<<768, 256, 0, stream>>>(Qf, Kfh, Kfl, xh, xw);
    small_ops<<<1, 1024, 0, stream>>>(xh, xw, c1w, gam, bet, chw, cww, y, sh, sw);
    attn_pv<<<dim3(8, BH_), 256, 0, stream>>>(Qf, Kfh, Kfl, v, mask, sh, sw, out);
}

// Round 8
// 226.086 us; speedup vs baseline: 1.6850x; 1.2183x over previous
//
#include <hip/hip_runtime.h>
#include <math.h>

#define B_   8
#define S_   512
#define DM_  768
#define H_   12
#define D_   64
#define BH_  96
#define M_   4096   // B_*S_

typedef _Float16 f16x8 __attribute__((ext_vector_type(8)));
typedef float    f32x4 __attribute__((ext_vector_type(4)));

__device__ __forceinline__ float dual_spike(float x) {
    return x >= 1.0f ? 1.0f : (x <= -1.0f ? -1.0f : 0.0f);
}

__device__ __forceinline__ void gload_lds16(const void* g, void* l) {
    __builtin_amdgcn_global_load_lds(
        (const __attribute__((address_space(1))) unsigned int*)g,
        (__attribute__((address_space(3))) unsigned int*)l, 16, 0, 0);
}

// Shared QK dot chain — MUST be bitwise identical wherever t is derived.
// acc holds 256 * dot (k planes are scaled x256). Threshold: dot>=8 <=> acc>=2048.
__device__ __forceinline__ f32x4 qk_dot(const f16x8* qa, const f16x8* kh, const f16x8* kl) {
    f32x4 acc = (f32x4){0.f, 0.f, 0.f, 0.f};
    acc = __builtin_amdgcn_mfma_f32_16x16x32_f16(qa[0], kh[0], acc, 0, 0, 0);
    acc = __builtin_amdgcn_mfma_f32_16x16x32_f16(qa[0], kl[0], acc, 0, 0, 0);
    acc = __builtin_amdgcn_mfma_f32_16x16x32_f16(qa[1], kh[1], acc, 0, 0, 0);
    acc = __builtin_amdgcn_mfma_f32_16x16x32_f16(qa[1], kl[1], acc, 0, 0, 0);
    return acc;
}

// ---------------- Prepass: X -> fp16 hi/lo planes, fragment-major tile order ----
__global__ __launch_bounds__(256) void prep_x(
    const float* __restrict__ X, _Float16* __restrict__ Xh, _Float16* __restrict__ Xl)
{
    int wid  = blockIdx.x * 4 + (threadIdx.x >> 6);
    int lane = threadIdx.x & 63;
    int fm = wid & 7, kc = (wid >> 3) % 24, mb = wid / 192;
    int row = mb * 128 + fm * 16 + (lane & 15);
    int col = kc * 32 + (lane >> 4) * 8;
    const float4* p = reinterpret_cast<const float4*>(&X[row * DM_ + col]);
    float4 x0 = p[0], x1 = p[1];
    float xs[8] = {x0.x, x0.y, x0.z, x0.w, x1.x, x1.y, x1.z, x1.w};
    f16x8 hi, lo;
    #pragma unroll
    for (int j = 0; j < 8; ++j) {
        float v = xs[j] * 256.0f;
        _Float16 h = (_Float16)v;
        hi[j] = h;
        lo[j] = (_Float16)(v - (float)h);
    }
    size_t out = ((size_t)wid * 64 + lane) * 8;
    *reinterpret_cast<f16x8*>(&Xh[out]) = hi;
    *reinterpret_cast<f16x8*>(&Xl[out]) = lo;
}

// ---------------- Prepass: W (q,k,v) -> transposed fp16 hi/lo planes ------------
__global__ __launch_bounds__(256) void prep_w(
    const float* __restrict__ Wq, const float* __restrict__ Wk, const float* __restrict__ Wv,
    _Float16* __restrict__ Wth, _Float16* __restrict__ Wtl)
{
    int wid  = blockIdx.x * 4 + (threadIdx.x >> 6);
    int lane = threadIdx.x & 63;
    int fn = wid & 7, kc = (wid >> 3) % 24;
    int nb = (wid >> 3) / 24 % 6, which = wid / 1152;
    const float* __restrict__ W = which == 0 ? Wq : (which == 1 ? Wk : Wv);
    int c = lane & 15, g = lane >> 4;
    int ncol = nb * 128 + fn * 16 + c;
    int krow = kc * 32 + g * 8;
    f16x8 hi, lo;
    #pragma unroll
    for (int j = 0; j < 8; ++j) {
        float v = W[(krow + j) * DM_ + ncol] * 256.0f;
        _Float16 h = (_Float16)v;
        hi[j] = h;
        lo[j] = (_Float16)(v - (float)h);
    }
    size_t out = ((size_t)wid * 64 + lane) * 8;
    *reinterpret_cast<f16x8*>(&Wth[out]) = hi;
    *reinterpret_cast<f16x8*>(&Wtl[out]) = lo;
}

// ---------------- Kernel 1: QKV projections via fp16 split MFMA ----------------
// v7: L2-sized XCD epochs — each XCD works (4 mb x 6 nb, fixed which) groups:
// working set 4x393KB (A) + 6x393KB (B) ~= 4.0 MB ~= per-XCD L2. Previous chunking
// spanned 12 mb panels (~7 MB) -> L2 thrash -> L3-latency-bound iterations.
__global__ __launch_bounds__(256, 2) void qkv_mfma(
    const _Float16* __restrict__ Xh, const _Float16* __restrict__ Xl,
    const _Float16* __restrict__ Wth, const _Float16* __restrict__ Wtl,
    const float* __restrict__ X,
    const float* __restrict__ Wq, const float* __restrict__ bq,
    const float* __restrict__ Wk, const float* __restrict__ bk,
    const float* __restrict__ Wv, const float* __restrict__ bv,
    float* __restrict__ q, float* __restrict__ k, float* __restrict__ v)
{
    const int orig = blockIdx.x;
    const int xcd = orig & 7, idx = orig >> 3;      // HW round-robins XCDs on orig%8
    const int super = idx / 24, sub = idx % 24;     // 3 epochs x 24 blocks per XCD
    const int mw = xcd * 12 + super * 4 + sub / 6;  // 0..95 (bijective)
    const int which = mw >> 5, mb = mw & 31;
    const int nb = sub % 6;

    const float* __restrict__ bias = which == 0 ? bq : (which == 1 ? bk : bv);
    float* __restrict__ out        = which == 0 ? q  : (which == 1 ? k  : v);

    __shared__ __align__(16) float fixs[4][1536];

    const int tid = threadIdx.x;
    const int wave = tid >> 6, lane = tid & 63;
    const int wm = wave >> 1, wn = wave & 1;
    const int l15 = lane & 15, g = lane >> 4;

    const _Float16* __restrict__ pAh = Xh + (size_t)(mb * 24) * 4096 + wm * 2048 + g * 128 + l15 * 8;
    const _Float16* __restrict__ pAl = Xl + (size_t)(mb * 24) * 4096 + wm * 2048 + g * 128 + l15 * 8;
    const _Float16* __restrict__ pBh = Wth + (size_t)((which * 6 + nb) * 24) * 4096 + wn * 2048 + g * 128 + l15 * 8;
    const _Float16* __restrict__ pBl = Wtl + (size_t)((which * 6 + nb) * 24) * 4096 + wn * 2048 + g * 128 + l15 * 8;

    f32x4 acc[4][4];
    #pragma unroll
    for (int i = 0; i < 4; ++i)
        #pragma unroll
        for (int j = 0; j < 4; ++j) acc[i][j] = (f32x4){0.f, 0.f, 0.f, 0.f};

    f16x8 a0h[4], a0l[4], b0h[4], b0l[4];
    f16x8 a1h[4], a1l[4], b1h[4], b1l[4];

    auto loadfrag = [&](int kc, f16x8 (&ah)[4], f16x8 (&al)[4],
                                f16x8 (&bh)[4], f16x8 (&bl)[4]) {
        const size_t o = (size_t)kc * 4096;
        #pragma unroll
        for (int f = 0; f < 4; ++f) {
            ah[f] = *reinterpret_cast<const f16x8*>(pAh + o + f * 512);
            al[f] = *reinterpret_cast<const f16x8*>(pAl + o + f * 512);
            bh[f] = *reinterpret_cast<const f16x8*>(pBh + o + f * 512);
            bl[f] = *reinterpret_cast<const f16x8*>(pBl + o + f * 512);
        }
    };
    auto domfma = [&](f16x8 (&ah)[4], f16x8 (&al)[4],
                      f16x8 (&bh)[4], f16x8 (&bl)[4]) {
        #pragma unroll
        for (int i = 0; i < 4; ++i)
            #pragma unroll
            for (int j = 0; j < 4; ++j) {
                acc[i][j] = __builtin_amdgcn_mfma_f32_16x16x32_f16(ah[i], bh[j], acc[i][j], 0, 0, 0);
                acc[i][j] = __builtin_amdgcn_mfma_f32_16x16x32_f16(ah[i], bl[j], acc[i][j], 0, 0, 0);
                acc[i][j] = __builtin_amdgcn_mfma_f32_16x16x32_f16(al[i], bh[j], acc[i][j], 0, 0, 0);
            }
    };

    loadfrag(0, a0h, a0l, b0h, b0l);
    __builtin_amdgcn_sched_barrier(0);   // pin: buf0 loads issued before anything below
    for (int kc2 = 0; kc2 < 12; ++kc2) {
        loadfrag(2 * kc2 + 1, a1h, a1l, b1h, b1l);   // prefetch odd tile
        __builtin_amdgcn_sched_barrier(0);           // loads stay ABOVE the MFMAs
        domfma(a0h, a0l, b0h, b0l);                  // compute even tile
        __builtin_amdgcn_sched_barrier(0);
        if (kc2 < 11) {
            loadfrag(2 * kc2 + 2, a0h, a0l, b0h, b0l); // prefetch next even
        }
        __builtin_amdgcn_sched_barrier(0);
        domfma(a1h, a1l, b1h, b1l);                  // compute odd tile
        __builtin_amdgcn_sched_barrier(0);
    }

    const float* __restrict__ Worig = which == 0 ? Wq : (which == 1 ? Wk : Wv);
    float* __restrict__ fx = fixs[wave];

    #pragma unroll
    for (int i = 0; i < 4; ++i) {
        #pragma unroll
        for (int j = 0; j < 4; ++j) {
            int n = nb * 128 + wn * 64 + j * 16 + l15;
            int h = n >> 6, d = n & 63;
            float bn = bias[n];
            #pragma unroll
            for (int r = 0; r < 4; ++r) {
                int m = mb * 128 + wm * 64 + i * 16 + g * 4 + r;
                float val = acc[i][j][r] * (1.0f / 65536.0f) + bn;
                if (which < 2) {
                    bool need = fabsf(fabsf(val) - 1.0f) < 1e-4f;
                    unsigned long long msk = __ballot(need);
                    while (msk) {
                        int L = (int)__builtin_ctzll(msk);
                        msk &= msk - 1;
                        int Lm = mb * 128 + wm * 64 + i * 16 + (L >> 4) * 4 + r;
                        int Ln = nb * 128 + wn * 64 + j * 16 + (L & 15);
                        #pragma unroll
                        for (int t = 0; t < 12; ++t) {
                            int e = t * 64 + lane;
                            fx[e]       = X[Lm * DM_ + e];
                            fx[768 + e] = Worig[e * DM_ + Ln];
                        }
                        asm volatile("s_waitcnt vmcnt(0) lgkmcnt(0)" ::: "memory");
                        if (lane == L) {
                            float a2 = 0.0f;
                            for (int kk = 0; kk < DM_; ++kk)
                                a2 = fmaf(fx[kk], fx[768 + kk], a2);
                            val = a2 + bn;
                        }
                        asm volatile("s_waitcnt lgkmcnt(0)" ::: "memory");
                    }
                }
                if (which == 0)      val = dual_spike(val);
                else if (which == 1) val = 0.5f * dual_spike(val) + 0.5f * val;
                int b = m >> 9, s = m & 511;
                out[(((b * H_ + h) * S_) + s) * D_ + d] = val;
            }
        }
    }
}

// ---------------- Prepass: q,k -> MFMA fragment arrays -------------------------
__global__ __launch_bounds__(256) void prep_qk(
    const float* __restrict__ q, const float* __restrict__ k,
    _Float16* __restrict__ Qf, _Float16* __restrict__ Kfh, _Float16* __restrict__ Kfl)
{
    int wid  = blockIdx.x * 4 + (threadIdx.x >> 6);   // (bh*32 + s16)*2 + dc
    int lane = threadIdx.x & 63;
    int dc = wid & 1, s16 = (wid >> 1) & 31, bh = wid >> 6;
    int l15 = lane & 15, g = lane >> 4;
    int s = s16 * 16 + l15;
    int d0 = dc * 32 + g * 8;
    const float* qp = &q[((size_t)bh * S_ + s) * D_ + d0];
    const float* kp = &k[((size_t)bh * S_ + s) * D_ + d0];
    f16x8 qv, kh, kl;
    #pragma unroll
    for (int j = 0; j < 8; ++j) {
        qv[j] = (_Float16)qp[j];                 // exact: q in {-1,0,1}
        float val = kp[j] * 256.0f;
        _Float16 h = (_Float16)val;
        kh[j] = h;
        kl[j] = (_Float16)(val - (float)h);
    }
    size_t o = (size_t)wid * 512 + lane * 8;
    *reinterpret_cast<f16x8*>(&Qf[o])  = qv;
    *reinterpret_cast<f16x8*>(&Kfh[o]) = kh;
    *reinterpret_cast<f16x8*>(&Kfl[o]) = kl;
}

// ---------------- Kernel 2: score threshold counts via MFMA --------------------
__global__ __launch_bounds__(256) void score_sums(
    const _Float16* __restrict__ Qf, const _Float16* __restrict__ Kfh,
    const _Float16* __restrict__ Kfl,
    float* __restrict__ xh, float* __restrict__ xw)
{
    const int blk = blockIdx.x;
    const int qt = blk & 7, bh = blk >> 3;
    const int tid = threadIdx.x, wave = tid >> 6, lane = tid & 63;
    const int l15 = lane & 15, g = lane >> 4;

    __shared__ float rowred[4][64];

    f16x8 qa[4][2];
    #pragma unroll
    for (int sf = 0; sf < 4; ++sf) {
        const _Float16* qb = Qf + (size_t)((bh * 32 + qt * 4 + sf) * 2) * 512 + lane * 8;
        qa[sf][0] = *reinterpret_cast<const f16x8*>(qb);
        qa[sf][1] = *reinterpret_cast<const f16x8*>(qb + 512);
    }
    float rowc[4][4];
    #pragma unroll
    for (int sf = 0; sf < 4; ++sf)
        #pragma unroll
        for (int r = 0; r < 4; ++r) rowc[sf][r] = 0.0f;

    for (int sc8 = 0; sc8 < 8; ++sc8) {
        int scol16 = sc8 * 4 + wave;
        const _Float16* kbh = Kfh + (size_t)((bh * 32 + scol16) * 2) * 512 + lane * 8;
        const _Float16* kbl = Kfl + (size_t)((bh * 32 + scol16) * 2) * 512 + lane * 8;
        f16x8 kh[2] = {*reinterpret_cast<const f16x8*>(kbh),
                       *reinterpret_cast<const f16x8*>(kbh + 512)};
        f16x8 kl[2] = {*reinterpret_cast<const f16x8*>(kbl),
                       *reinterpret_cast<const f16x8*>(kbl + 512)};
        float csum = 0.0f;
        #pragma unroll
        for (int sf = 0; sf < 4; ++sf) {
            f32x4 acc = qk_dot(qa[sf], kh, kl);
            #pragma unroll
            for (int r = 0; r < 4; ++r) {
                float t1 = acc[r] >= 2048.0f ? 1.0f : 0.0f;   // dot >= 8
                rowc[sf][r] += t1;
                csum += t1;
            }
        }
        csum += __shfl_xor(csum, 16);
        csum += __shfl_xor(csum, 32);
        if (g == 0) atomicAdd(&xw[bh * S_ + scol16 * 16 + l15], csum);
    }
    #pragma unroll
    for (int sf = 0; sf < 4; ++sf)
        #pragma unroll
        for (int r = 0; r < 4; ++r) {
            float sv = rowc[sf][r];
            sv += __shfl_xor(sv, 1); sv += __shfl_xor(sv, 2);
            sv += __shfl_xor(sv, 4); sv += __shfl_xor(sv, 8);
            if (l15 == 0) rowred[wave][sf * 16 + g * 4 + r] = sv;
        }
    __syncthreads();
    if (tid < 64) {
        float sv = rowred[0][tid] + rowred[1][tid] + rowred[2][tid] + rowred[3][tid];
        xh[bh * S_ + qt * 64 + tid] = sv;    // exact count, no atomics needed
    }
}

// ---------------- Kernel 3a: conv1 y + per-block partial stats (deterministic) --
__global__ __launch_bounds__(256) void small_a(
    const float* __restrict__ xh, const float* __restrict__ xw,
    const float* __restrict__ c1w,
    float* __restrict__ y, float* __restrict__ stats_part)   // [24][2]
{
    const int tid = threadIdx.x;
    const int br = blockIdx.x;           // b*3 + r
    const int r = br % 3, b = br / 3;
    __shared__ float c1s[12];
    __shared__ float red[256], red2[256];
    if (tid < 12) c1s[tid] = c1w[r * 12 + tid];
    __syncthreads();

    float psum = 0.0f, psq = 0.0f;
    for (int n = tid; n < 1024; n += 256) {
        float acc = 0.0f;
        #pragma unroll
        for (int h = 0; h < 12; ++h) {
            float cv = (n < 512) ? xh[(b * H_ + h) * S_ + n]
                                 : xw[(b * H_ + h) * S_ + (n - 512)];
            acc = fmaf(c1s[h], cv * (1.0f / 512.0f), acc);
        }
        y[br * 1024 + n] = acc;
        psum += acc;
        psq = fmaf(acc, acc, psq);
    }
    red[tid] = psum; red2[tid] = psq;
    __syncthreads();
    for (int o = 128; o > 0; o >>= 1) {
        if (tid < o) { red[tid] += red[tid + o]; red2[tid] += red2[tid + o]; }
        __syncthreads();
    }
    if (tid == 0) {
        stats_part[br * 2 + 0] = red[0];
        stats_part[br * 2 + 1] = red2[0];
    }
}

// ---------------- Kernel 3b: BN + relu + conv + sigmoid ------------------------
__global__ __launch_bounds__(512) void small_b(
    const float* __restrict__ y, const float* __restrict__ stats_part,
    const float* __restrict__ gamma, const float* __restrict__ beta,
    const float* __restrict__ chw, const float* __restrict__ cww,
    float* __restrict__ s_h, float* __restrict__ s_w)
{
    int e = blockIdx.x * 512 + threadIdx.x;   // 0..49151
    int s = e & 511; int bh = e >> 9; int h = bh % H_; int b = bh / H_;
    float ah = 0.0f, aw = 0.0f;
    #pragma unroll
    for (int r = 0; r < 3; ++r) {
        float su = 0.0f, sq = 0.0f;
        #pragma unroll
        for (int bb = 0; bb < 8; ++bb) {     // fixed order -> deterministic
            su += stats_part[(bb * 3 + r) * 2 + 0];
            sq += stats_part[(bb * 3 + r) * 2 + 1];
        }
        float mu = su * (1.0f / 8192.0f);
        float var = sq * (1.0f / 8192.0f) - mu * mu;
        float rs = rsqrtf(var + 1e-5f);
        int yb = (b * 3 + r) << 10;
        float yh = fmaxf((y[yb + s]       - mu) * rs * gamma[r] + beta[r], 0.0f);
        float yw = fmaxf((y[yb + 512 + s] - mu) * rs * gamma[r] + beta[r], 0.0f);
        ah = fmaf(chw[h * 3 + r], yh, ah);
        aw = fmaf(cww[h * 3 + r], yw, aw);
    }
    s_h[e] = 1.0f / (1.0f + expf(-ah));
    s_w[e] = 1.0f / (1.0f + expf(-aw));
}

// ---------------- Kernel 4: MFMA QK^T + bias + online softmax + VALU PV --------
// v7 schedule (T14): K(kt+1) staged after the post-QK barrier (hides under
// softmax+PV); V(kt+1) staged after the post-PV barrier (hides under next QK).
// No load is issued-then-immediately-drained. Still 2 barriers/iter.
__global__ __launch_bounds__(256) void attn_pv(
    const _Float16* __restrict__ Qf, const _Float16* __restrict__ Kfh,
    const _Float16* __restrict__ Kfl, const float* __restrict__ v,
    const float* __restrict__ mask, const float* __restrict__ s_h,
    const float* __restrict__ s_w, float* __restrict__ out)
{
    __shared__ __align__(16) float Vs[4096];            // [kk][64] fp32
    __shared__ __align__(16) _Float16 Kst[2][4096];     // K frag planes for this tile
    __shared__ __align__(16) float P_lds[64][68];

    const int bh = blockIdx.y, b = bh / H_, h = bh % H_;
    const int qt = blockIdx.x, q0 = qt * 64;
    const int tid = threadIdx.x, wave = tid >> 6, lane = tid & 63;
    const int l15 = lane & 15, g = lane >> 4;
    const int rl = wave * 16 + g * 4;                   // + reg -> local q row

    const _Float16* qb = Qf + (size_t)((bh * 32 + qt * 4 + wave) * 2) * 512 + lane * 8;
    f16x8 qa[2] = {*reinterpret_cast<const f16x8*>(qb),
                   *reinterpret_cast<const f16x8*>(qb + 512)};

    float shq[4];
    #pragma unroll
    for (int r = 0; r < 4; ++r) shq[r] = s_h[bh * S_ + q0 + rl + r];

    auto stageK = [&](int kt) {
        const _Float16* sh_ = Kfh + (size_t)((bh * 32 + kt * 4) * 2) * 512;
        const _Float16* sl_ = Kfl + (size_t)((bh * 32 + kt * 4) * 2) * 512;
        #pragma unroll
        for (int c = 0; c < 2; ++c) {
            int u = (c * 4 + wave) * 512;           // halves
            gload_lds16(&sh_[u + lane * 8], &Kst[0][u]);
            gload_lds16(&sl_[u + lane * 8], &Kst[1][u]);
        }
    };
    auto stageV = [&](int kt) {
        const float* vsrc = v + ((size_t)bh * S_ + kt * 64) * D_;
        #pragma unroll
        for (int c = 0; c < 4; ++c) {
            int u = (c * 4 + wave) * 256;           // floats
            gload_lds16(&vsrc[u + lane * 4], &Vs[u]);
        }
    };

    float m_r[4], l_r[4];
    f32x4 ctx[4];
    #pragma unroll
    for (int r = 0; r < 4; ++r) {
        m_r[r] = -INFINITY; l_r[r] = 0.0f;
        ctx[r] = (f32x4){0.f, 0.f, 0.f, 0.f};
    }

    stageK(0); stageV(0);
    __syncthreads();    // prologue drain

    for (int kt = 0; kt < 8; ++kt) {
        // --- QK^T (reads Kst; V(kt) was drained at the last barrier) ---
        float sc[4][4];     // [fc][reg]
        #pragma unroll
        for (int fc = 0; fc < 4; ++fc) {
            f16x8 kh[2] = {*reinterpret_cast<const f16x8*>(&Kst[0][(fc * 2 + 0) * 512 + lane * 8]),
                           *reinterpret_cast<const f16x8*>(&Kst[0][(fc * 2 + 1) * 512 + lane * 8])};
            f16x8 kl[2] = {*reinterpret_cast<const f16x8*>(&Kst[1][(fc * 2 + 0) * 512 + lane * 8]),
                           *reinterpret_cast<const f16x8*>(&Kst[1][(fc * 2 + 1) * 512 + lane * 8])};
            f32x4 acc = qk_dot(qa, kh, kl);
            int col = kt * 64 + fc * 16 + l15;
            float mj  = mask[b * S_ + col];
            float swj = s_w[bh * S_ + col];
            #pragma unroll
            for (int r = 0; r < 4; ++r) {
                float t1 = acc[r] >= 2048.0f ? 1.0f : 0.0f;   // same chain as score_sums
                sc[fc][r] = acc[r] * 4.8828125e-4f + mj + t1 * (shq[r] * swj);
            }
        }
        __syncthreads();            // A: all waves done reading Kst
        if (kt < 7) stageK(kt + 1); // K loads fly under softmax + PV

        // --- online softmax ---
        float p[4][4], cscale[4];
        #pragma unroll
        for (int r = 0; r < 4; ++r) {
            float tmax = fmaxf(fmaxf(sc[0][r], sc[1][r]), fmaxf(sc[2][r], sc[3][r]));
            tmax = fmaxf(tmax, __shfl_xor(tmax, 1));
            tmax = fmaxf(tmax, __shfl_xor(tmax, 2));
            tmax = fmaxf(tmax, __shfl_xor(tmax, 4));
            tmax = fmaxf(tmax, __shfl_xor(tmax, 8));
            float mn = fmaxf(m_r[r], tmax);
            float ps = 0.0f;
            #pragma unroll
            for (int fc = 0; fc < 4; ++fc) { p[fc][r] = expf(sc[fc][r] - mn); ps += p[fc][r]; }
            ps += __shfl_xor(ps, 1); ps += __shfl_xor(ps, 2);
            ps += __shfl_xor(ps, 4); ps += __shfl_xor(ps, 8);
            float scale = expf(m_r[r] - mn);
            l_r[r] = l_r[r] * scale + ps;
            m_r[r] = mn;
            cscale[r] = scale;
        }
        // P to LDS: each wave writes & reads only its own 16 rows (no barrier needed)
        #pragma unroll
        for (int fc = 0; fc < 4; ++fc)
            #pragma unroll
            for (int r = 0; r < 4; ++r)
                P_lds[rl + r][fc * 16 + l15] = p[fc][r];

        #pragma unroll
        for (int r = 0; r < 4; ++r) ctx[r] *= cscale[r];

        // --- PV (reads Vs + P_lds) ---
        #pragma unroll
        for (int kk4 = 0; kk4 < 16; ++kk4) {
            f32x4 pr0 = *reinterpret_cast<const f32x4*>(&P_lds[rl + 0][kk4 * 4]);
            f32x4 pr1 = *reinterpret_cast<const f32x4*>(&P_lds[rl + 1][kk4 * 4]);
            f32x4 pr2 = *reinterpret_cast<const f32x4*>(&P_lds[rl + 2][kk4 * 4]);
            f32x4 pr3 = *reinterpret_cast<const f32x4*>(&P_lds[rl + 3][kk4 * 4]);
            f32x4 vv0 = *reinterpret_cast<const f32x4*>(&Vs[(kk4 * 4 + 0) * 64 + l15 * 4]);
            f32x4 vv1 = *reinterpret_cast<const f32x4*>(&Vs[(kk4 * 4 + 1) * 64 + l15 * 4]);
            f32x4 vv2 = *reinterpret_cast<const f32x4*>(&Vs[(kk4 * 4 + 2) * 64 + l15 * 4]);
            f32x4 vv3 = *reinterpret_cast<const f32x4*>(&Vs[(kk4 * 4 + 3) * 64 + l15 * 4]);
            ctx[0] += pr0[0] * vv0; ctx[0] += pr0[1] * vv1; ctx[0] += pr0[2] * vv2; ctx[0] += pr0[3] * vv3;
            ctx[1] += pr1[0] * vv0; ctx[1] += pr1[1] * vv1; ctx[1] += pr1[2] * vv2; ctx[1] += pr1[3] * vv3;
            ctx[2] += pr2[0] * vv0; ctx[2] += pr2[1] * vv1; ctx[2] += pr2[2] * vv2; ctx[2] += pr2[3] * vv3;
            ctx[3] += pr3[0] * vv0; ctx[3] += pr3[1] * vv1; ctx[3] += pr3[2] * vv2; ctx[3] += pr3[3] * vv3;
        }
        __syncthreads();            // B: drains K(kt+1); all waves done reading Vs
        if (kt < 7) stageV(kt + 1); // V loads fly under next QK^T; drained at next A
    }
    #pragma unroll
    for (int r = 0; r < 4; ++r) {
        int s = q0 + rl + r;
        float inv = 1.0f / l_r[r];
        f32x4 o = ctx[r] * inv;
        *reinterpret_cast<f32x4*>(&out[((size_t)b * S_ + s) * DM_ + h * D_ + l15 * 4]) = o;
    }
}

extern "C" void kernel_launch(void* const* d_in, const int* in_sizes, int n_in,
                              void* d_out, int out_size, void* d_ws, size_t ws_size,
                              hipStream_t stream) {
    const float* X    = (const float*)d_in[0];
    const float* mask = (const float*)d_in[1];
    const float* Wq   = (const float*)d_in[2];
    const float* bq   = (const float*)d_in[3];
    const float* Wk   = (const float*)d_in[4];
    const float* bk   = (const float*)d_in[5];
    const float* Wv   = (const float*)d_in[6];
    const float* bv   = (const float*)d_in[7];
    const float* c1w  = (const float*)d_in[8];
    const float* gam  = (const float*)d_in[9];
    const float* bet  = (const float*)d_in[10];
    const float* chw  = (const float*)d_in[11];
    const float* cww  = (const float*)d_in[12];
    float* out = (float*)d_out;

    float* ws = (float*)d_ws;
    float* q  = ws;                        // 3145728 f32 (dead after prep_qk)
    float* k  = q  + 3145728;
    float* v  = k  + 3145728;
    float* xh = v  + 3145728;              // 49152
    float* xw = xh + 49152;
    float* y  = xw + 49152;                // 24576
    float* sh = y  + 24576;
    float* sw = sh + 49152;
    _Float16* Xh  = (_Float16*)(sw + 49152);   // 3145728 halves
    _Float16* Xl  = Xh + 3145728;
    _Float16* Wth = Xl + 3145728;              // 1769472 halves
    _Float16* Wtl = Wth + 1769472;             // total ws ~55.6 MiB

    // Fragment arrays for score/attn overlay the (dead-after-qkv) staging planes:
    _Float16* Qf  = Xh;                        // 3145728 halves
    _Float16* Kfh = Xl;                        // 3145728 halves
    _Float16* Kfl = Wth;                       // 3145728 halves (spans Wth+Wtl)
    float* stats_part = q;                     // 48 floats, q is dead by small_a

    hipMemsetAsync(xw, 0, 49152 * sizeof(float), stream);

    prep_x<<<1536, 256, 0, stream>>>(X, Xh, Xl);
    prep_w<<<864, 256, 0, stream>>>(Wq, Wk, Wv, Wth, Wtl);
    qkv_mfma<<<576, 256, 0, stream>>>(Xh, Xl, Wth, Wtl,
        X, Wq, bq, Wk, bk, Wv, bv, q, k, v);
    prep_qk<<<1536, 256, 0, stream>>>(q, k, Qf, Kfh, Kfl);
    score_sums<<<768, 256, 0, stream>>>(Qf, Kfh, Kfl, xh, xw);
    small_a<<<24, 256, 0, stream>>>(xh, xw, c1w, y, stats_part);
    small_b<<<96, 512, 0, stream>>>(y, stats_part, gam, bet, chw, cww, sh, sw);
    attn_pv<<<dim3(8, BH_), 256, 0, stream>>>(Qf, Kfh, Kfl, v, mask, sh, sw, out);
}

// Round 9
// 181.607 us; speedup vs baseline: 2.0977x; 1.2449x over previous
//
#include <hip/hip_runtime.h>
#include <math.h>

#define B_   8
#define S_   512
#define DM_  768
#define H_   12
#define D_   64
#define BH_  96
#define M_   4096   // B_*S_

typedef _Float16 f16x8 __attribute__((ext_vector_type(8)));
typedef float    f32x4 __attribute__((ext_vector_type(4)));

__device__ __forceinline__ float dual_spike(float x) {
    return x >= 1.0f ? 1.0f : (x <= -1.0f ? -1.0f : 0.0f);
}

__device__ __forceinline__ void gload_lds16(const void* g, void* l) {
    __builtin_amdgcn_global_load_lds(
        (const __attribute__((address_space(1))) unsigned int*)g,
        (__attribute__((address_space(3))) unsigned int*)l, 16, 0, 0);
}

// Shared QK dot chain — MUST be bitwise identical wherever t is derived.
// acc holds 256 * dot (k planes are scaled x256). Threshold: dot>=8 <=> acc>=2048.
__device__ __forceinline__ f32x4 qk_dot(const f16x8* qa, const f16x8* kh, const f16x8* kl) {
    f32x4 acc = (f32x4){0.f, 0.f, 0.f, 0.f};
    acc = __builtin_amdgcn_mfma_f32_16x16x32_f16(qa[0], kh[0], acc, 0, 0, 0);
    acc = __builtin_amdgcn_mfma_f32_16x16x32_f16(qa[0], kl[0], acc, 0, 0, 0);
    acc = __builtin_amdgcn_mfma_f32_16x16x32_f16(qa[1], kh[1], acc, 0, 0, 0);
    acc = __builtin_amdgcn_mfma_f32_16x16x32_f16(qa[1], kl[1], acc, 0, 0, 0);
    return acc;
}

// ---------------- Prepass: X -> fp16 hi/lo planes, fragment-major tile order ----
__global__ __launch_bounds__(256) void prep_x(
    const float* __restrict__ X, _Float16* __restrict__ Xh, _Float16* __restrict__ Xl)
{
    int wid  = blockIdx.x * 4 + (threadIdx.x >> 6);
    int lane = threadIdx.x & 63;
    int fm = wid & 7, kc = (wid >> 3) % 24, mb = wid / 192;
    int row = mb * 128 + fm * 16 + (lane & 15);
    int col = kc * 32 + (lane >> 4) * 8;
    const float4* p = reinterpret_cast<const float4*>(&X[row * DM_ + col]);
    float4 x0 = p[0], x1 = p[1];
    float xs[8] = {x0.x, x0.y, x0.z, x0.w, x1.x, x1.y, x1.z, x1.w};
    f16x8 hi, lo;
    #pragma unroll
    for (int j = 0; j < 8; ++j) {
        float v = xs[j] * 256.0f;
        _Float16 h = (_Float16)v;
        hi[j] = h;
        lo[j] = (_Float16)(v - (float)h);
    }
    size_t out = ((size_t)wid * 64 + lane) * 8;
    *reinterpret_cast<f16x8*>(&Xh[out]) = hi;
    *reinterpret_cast<f16x8*>(&Xl[out]) = lo;
}

// ---------------- Prepass: W (q,k,v) -> transposed fp16 hi/lo planes ------------
__global__ __launch_bounds__(256) void prep_w(
    const float* __restrict__ Wq, const float* __restrict__ Wk, const float* __restrict__ Wv,
    _Float16* __restrict__ Wth, _Float16* __restrict__ Wtl)
{
    int wid  = blockIdx.x * 4 + (threadIdx.x >> 6);
    int lane = threadIdx.x & 63;
    int fn = wid & 7, kc = (wid >> 3) % 24;
    int nb = (wid >> 3) / 24 % 6, which = wid / 1152;
    const float* __restrict__ W = which == 0 ? Wq : (which == 1 ? Wk : Wv);
    int c = lane & 15, g = lane >> 4;
    int ncol = nb * 128 + fn * 16 + c;
    int krow = kc * 32 + g * 8;
    f16x8 hi, lo;
    #pragma unroll
    for (int j = 0; j < 8; ++j) {
        float v = W[(krow + j) * DM_ + ncol] * 256.0f;
        _Float16 h = (_Float16)v;
        hi[j] = h;
        lo[j] = (_Float16)(v - (float)h);
    }
    size_t out = ((size_t)wid * 64 + lane) * 8;
    *reinterpret_cast<f16x8*>(&Wth[out]) = hi;
    *reinterpret_cast<f16x8*>(&Wtl[out]) = lo;
}

// ---------------- Kernel 1: QKV projections via fp16 split MFMA (R8, unchanged) --
__global__ __launch_bounds__(256, 2) void qkv_mfma(
    const _Float16* __restrict__ Xh, const _Float16* __restrict__ Xl,
    const _Float16* __restrict__ Wth, const _Float16* __restrict__ Wtl,
    const float* __restrict__ X,
    const float* __restrict__ Wq, const float* __restrict__ bq,
    const float* __restrict__ Wk, const float* __restrict__ bk,
    const float* __restrict__ Wv, const float* __restrict__ bv,
    float* __restrict__ q, float* __restrict__ k, float* __restrict__ v)
{
    const int orig = blockIdx.x;
    const int xcd = orig & 7, idx = orig >> 3;      // HW round-robins XCDs on orig%8
    const int super = idx / 24, sub = idx % 24;     // 3 epochs x 24 blocks per XCD
    const int mw = xcd * 12 + super * 4 + sub / 6;  // 0..95 (bijective)
    const int which = mw >> 5, mb = mw & 31;
    const int nb = sub % 6;

    const float* __restrict__ bias = which == 0 ? bq : (which == 1 ? bk : bv);
    float* __restrict__ out        = which == 0 ? q  : (which == 1 ? k  : v);

    __shared__ __align__(16) float fixs[4][1536];

    const int tid = threadIdx.x;
    const int wave = tid >> 6, lane = tid & 63;
    const int wm = wave >> 1, wn = wave & 1;
    const int l15 = lane & 15, g = lane >> 4;

    const _Float16* __restrict__ pAh = Xh + (size_t)(mb * 24) * 4096 + wm * 2048 + g * 128 + l15 * 8;
    const _Float16* __restrict__ pAl = Xl + (size_t)(mb * 24) * 4096 + wm * 2048 + g * 128 + l15 * 8;
    const _Float16* __restrict__ pBh = Wth + (size_t)((which * 6 + nb) * 24) * 4096 + wn * 2048 + g * 128 + l15 * 8;
    const _Float16* __restrict__ pBl = Wtl + (size_t)((which * 6 + nb) * 24) * 4096 + wn * 2048 + g * 128 + l15 * 8;

    f32x4 acc[4][4];
    #pragma unroll
    for (int i = 0; i < 4; ++i)
        #pragma unroll
        for (int j = 0; j < 4; ++j) acc[i][j] = (f32x4){0.f, 0.f, 0.f, 0.f};

    f16x8 a0h[4], a0l[4], b0h[4], b0l[4];
    f16x8 a1h[4], a1l[4], b1h[4], b1l[4];

    auto loadfrag = [&](int kc, f16x8 (&ah)[4], f16x8 (&al)[4],
                                f16x8 (&bh)[4], f16x8 (&bl)[4]) {
        const size_t o = (size_t)kc * 4096;
        #pragma unroll
        for (int f = 0; f < 4; ++f) {
            ah[f] = *reinterpret_cast<const f16x8*>(pAh + o + f * 512);
            al[f] = *reinterpret_cast<const f16x8*>(pAl + o + f * 512);
            bh[f] = *reinterpret_cast<const f16x8*>(pBh + o + f * 512);
            bl[f] = *reinterpret_cast<const f16x8*>(pBl + o + f * 512);
        }
    };
    auto domfma = [&](f16x8 (&ah)[4], f16x8 (&al)[4],
                      f16x8 (&bh)[4], f16x8 (&bl)[4]) {
        #pragma unroll
        for (int i = 0; i < 4; ++i)
            #pragma unroll
            for (int j = 0; j < 4; ++j) {
                acc[i][j] = __builtin_amdgcn_mfma_f32_16x16x32_f16(ah[i], bh[j], acc[i][j], 0, 0, 0);
                acc[i][j] = __builtin_amdgcn_mfma_f32_16x16x32_f16(ah[i], bl[j], acc[i][j], 0, 0, 0);
                acc[i][j] = __builtin_amdgcn_mfma_f32_16x16x32_f16(al[i], bh[j], acc[i][j], 0, 0, 0);
            }
    };

    loadfrag(0, a0h, a0l, b0h, b0l);
    __builtin_amdgcn_sched_barrier(0);   // pin: buf0 loads issued before anything below
    for (int kc2 = 0; kc2 < 12; ++kc2) {
        loadfrag(2 * kc2 + 1, a1h, a1l, b1h, b1l);   // prefetch odd tile
        __builtin_amdgcn_sched_barrier(0);           // loads stay ABOVE the MFMAs
        domfma(a0h, a0l, b0h, b0l);                  // compute even tile
        __builtin_amdgcn_sched_barrier(0);
        if (kc2 < 11) {
            loadfrag(2 * kc2 + 2, a0h, a0l, b0h, b0l); // prefetch next even
        }
        __builtin_amdgcn_sched_barrier(0);
        domfma(a1h, a1l, b1h, b1l);                  // compute odd tile
        __builtin_amdgcn_sched_barrier(0);
    }

    const float* __restrict__ Worig = which == 0 ? Wq : (which == 1 ? Wk : Wv);
    float* __restrict__ fx = fixs[wave];

    #pragma unroll
    for (int i = 0; i < 4; ++i) {
        #pragma unroll
        for (int j = 0; j < 4; ++j) {
            int n = nb * 128 + wn * 64 + j * 16 + l15;
            int h = n >> 6, d = n & 63;
            float bn = bias[n];
            #pragma unroll
            for (int r = 0; r < 4; ++r) {
                int m = mb * 128 + wm * 64 + i * 16 + g * 4 + r;
                float val = acc[i][j][r] * (1.0f / 65536.0f) + bn;
                if (which < 2) {
                    bool need = fabsf(fabsf(val) - 1.0f) < 1e-4f;
                    unsigned long long msk = __ballot(need);
                    while (msk) {
                        int L = (int)__builtin_ctzll(msk);
                        msk &= msk - 1;
                        int Lm = mb * 128 + wm * 64 + i * 16 + (L >> 4) * 4 + r;
                        int Ln = nb * 128 + wn * 64 + j * 16 + (L & 15);
                        #pragma unroll
                        for (int t = 0; t < 12; ++t) {
                            int e = t * 64 + lane;
                            fx[e]       = X[Lm * DM_ + e];
                            fx[768 + e] = Worig[e * DM_ + Ln];
                        }
                        asm volatile("s_waitcnt vmcnt(0) lgkmcnt(0)" ::: "memory");
                        if (lane == L) {
                            float a2 = 0.0f;
                            for (int kk = 0; kk < DM_; ++kk)
                                a2 = fmaf(fx[kk], fx[768 + kk], a2);
                            val = a2 + bn;
                        }
                        asm volatile("s_waitcnt lgkmcnt(0)" ::: "memory");
                    }
                }
                if (which == 0)      val = dual_spike(val);
                else if (which == 1) val = 0.5f * dual_spike(val) + 0.5f * val;
                int b = m >> 9, s = m & 511;
                out[(((b * H_ + h) * S_) + s) * D_ + d] = val;
            }
        }
    }
}

// ---------------- Prepass: q,k -> MFMA fragment arrays -------------------------
__global__ __launch_bounds__(256) void prep_qk(
    const float* __restrict__ q, const float* __restrict__ k,
    _Float16* __restrict__ Qf, _Float16* __restrict__ Kfh, _Float16* __restrict__ Kfl)
{
    int wid  = blockIdx.x * 4 + (threadIdx.x >> 6);   // (bh*32 + s16)*2 + dc
    int lane = threadIdx.x & 63;
    int dc = wid & 1, s16 = (wid >> 1) & 31, bh = wid >> 6;
    int l15 = lane & 15, g = lane >> 4;
    int s = s16 * 16 + l15;
    int d0 = dc * 32 + g * 8;
    const float* qp = &q[((size_t)bh * S_ + s) * D_ + d0];
    const float* kp = &k[((size_t)bh * S_ + s) * D_ + d0];
    f16x8 qv, kh, kl;
    #pragma unroll
    for (int j = 0; j < 8; ++j) {
        qv[j] = (_Float16)qp[j];                 // exact: q in {-1,0,1}
        float val = kp[j] * 256.0f;
        _Float16 h = (_Float16)val;
        kh[j] = h;
        kl[j] = (_Float16)(val - (float)h);
    }
    size_t o = (size_t)wid * 512 + lane * 8;
    *reinterpret_cast<f16x8*>(&Qf[o])  = qv;
    *reinterpret_cast<f16x8*>(&Kfh[o]) = kh;
    *reinterpret_cast<f16x8*>(&Kfl[o]) = kl;
}

// ---------------- Prepass: v -> B-fragment hi/lo planes for PV -----------------
// Frag unit (bh, kc, d16): lane l15 -> d = d16*16+l15, g*8+j -> k = kc*32+g*8+j.
// Layout: [bh 96][kc 16][d16 4][512 halves].
__global__ __launch_bounds__(256) void prep_v(
    const float* __restrict__ v, _Float16* __restrict__ Vfh, _Float16* __restrict__ Vfl)
{
    int wid  = blockIdx.x * 4 + (threadIdx.x >> 6);   // (bh*16 + kc)*4 + d16
    int lane = threadIdx.x & 63;
    int d16 = wid & 3, kc = (wid >> 2) & 15, bh = wid >> 6;
    int l15 = lane & 15, g = lane >> 4;
    int d = d16 * 16 + l15;
    int k0 = kc * 32 + g * 8;
    const float* vp = &v[((size_t)bh * S_ + k0) * D_ + d];
    f16x8 hi, lo;
    #pragma unroll
    for (int j = 0; j < 8; ++j) {
        float val = vp[j * D_];
        _Float16 h = (_Float16)val;
        hi[j] = h;
        lo[j] = (_Float16)(val - (float)h);
    }
    size_t o = (size_t)wid * 512 + lane * 8;
    *reinterpret_cast<f16x8*>(&Vfh[o]) = hi;
    *reinterpret_cast<f16x8*>(&Vfl[o]) = lo;
}

// ---------------- Kernel 2: score threshold counts via MFMA --------------------
// bh-grouped XCD swizzle: each XCD owns 12 complete bh (all 8 qt) -> K L2 reuse.
__global__ __launch_bounds__(256) void score_sums(
    const _Float16* __restrict__ Qf, const _Float16* __restrict__ Kfh,
    const _Float16* __restrict__ Kfl,
    float* __restrict__ xh, float* __restrict__ xw)
{
    const int orig = blockIdx.x;
    const int xcd = orig & 7, idx = orig >> 3;
    const int bh = xcd * 12 + idx / 8, qt = idx & 7;
    const int tid = threadIdx.x, wave = tid >> 6, lane = tid & 63;
    const int l15 = lane & 15, g = lane >> 4;

    __shared__ float rowred[4][64];

    f16x8 qa[4][2];
    #pragma unroll
    for (int sf = 0; sf < 4; ++sf) {
        const _Float16* qb = Qf + (size_t)((bh * 32 + qt * 4 + sf) * 2) * 512 + lane * 8;
        qa[sf][0] = *reinterpret_cast<const f16x8*>(qb);
        qa[sf][1] = *reinterpret_cast<const f16x8*>(qb + 512);
    }
    float rowc[4][4];
    #pragma unroll
    for (int sf = 0; sf < 4; ++sf)
        #pragma unroll
        for (int r = 0; r < 4; ++r) rowc[sf][r] = 0.0f;

    for (int sc8 = 0; sc8 < 8; ++sc8) {
        int scol16 = sc8 * 4 + wave;
        const _Float16* kbh = Kfh + (size_t)((bh * 32 + scol16) * 2) * 512 + lane * 8;
        const _Float16* kbl = Kfl + (size_t)((bh * 32 + scol16) * 2) * 512 + lane * 8;
        f16x8 kh[2] = {*reinterpret_cast<const f16x8*>(kbh),
                       *reinterpret_cast<const f16x8*>(kbh + 512)};
        f16x8 kl[2] = {*reinterpret_cast<const f16x8*>(kbl),
                       *reinterpret_cast<const f16x8*>(kbl + 512)};
        float csum = 0.0f;
        #pragma unroll
        for (int sf = 0; sf < 4; ++sf) {
            f32x4 acc = qk_dot(qa[sf], kh, kl);
            #pragma unroll
            for (int r = 0; r < 4; ++r) {
                float t1 = acc[r] >= 2048.0f ? 1.0f : 0.0f;   // dot >= 8
                rowc[sf][r] += t1;
                csum += t1;
            }
        }
        csum += __shfl_xor(csum, 16);
        csum += __shfl_xor(csum, 32);
        if (g == 0) atomicAdd(&xw[bh * S_ + scol16 * 16 + l15], csum);
    }
    #pragma unroll
    for (int sf = 0; sf < 4; ++sf)
        #pragma unroll
        for (int r = 0; r < 4; ++r) {
            float sv = rowc[sf][r];
            sv += __shfl_xor(sv, 1); sv += __shfl_xor(sv, 2);
            sv += __shfl_xor(sv, 4); sv += __shfl_xor(sv, 8);
            if (l15 == 0) rowred[wave][sf * 16 + g * 4 + r] = sv;
        }
    __syncthreads();
    if (tid < 64) {
        float sv = rowred[0][tid] + rowred[1][tid] + rowred[2][tid] + rowred[3][tid];
        xh[bh * S_ + qt * 64 + tid] = sv;    // exact count, no atomics needed
    }
}

// ---------------- Kernel 3a: conv1 y + per-block partial stats (deterministic) --
__global__ __launch_bounds__(256) void small_a(
    const float* __restrict__ xh, const float* __restrict__ xw,
    const float* __restrict__ c1w,
    float* __restrict__ y, float* __restrict__ stats_part)   // [24][2]
{
    const int tid = threadIdx.x;
    const int br = blockIdx.x;           // b*3 + r
    const int r = br % 3, b = br / 3;
    __shared__ float c1s[12];
    __shared__ float red[256], red2[256];
    if (tid < 12) c1s[tid] = c1w[r * 12 + tid];
    __syncthreads();

    float psum = 0.0f, psq = 0.0f;
    for (int n = tid; n < 1024; n += 256) {
        float acc = 0.0f;
        #pragma unroll
        for (int h = 0; h < 12; ++h) {
            float cv = (n < 512) ? xh[(b * H_ + h) * S_ + n]
                                 : xw[(b * H_ + h) * S_ + (n - 512)];
            acc = fmaf(c1s[h], cv * (1.0f / 512.0f), acc);
        }
        y[br * 1024 + n] = acc;
        psum += acc;
        psq = fmaf(acc, acc, psq);
    }
    red[tid] = psum; red2[tid] = psq;
    __syncthreads();
    for (int o = 128; o > 0; o >>= 1) {
        if (tid < o) { red[tid] += red[tid + o]; red2[tid] += red2[tid + o]; }
        __syncthreads();
    }
    if (tid == 0) {
        stats_part[br * 2 + 0] = red[0];
        stats_part[br * 2 + 1] = red2[0];
    }
}

// ---------------- Kernel 3b: BN + relu + conv + sigmoid ------------------------
__global__ __launch_bounds__(512) void small_b(
    const float* __restrict__ y, const float* __restrict__ stats_part,
    const float* __restrict__ gamma, const float* __restrict__ beta,
    const float* __restrict__ chw, const float* __restrict__ cww,
    float* __restrict__ s_h, float* __restrict__ s_w)
{
    int e = blockIdx.x * 512 + threadIdx.x;   // 0..49151
    int s = e & 511; int bh = e >> 9; int h = bh % H_; int b = bh / H_;
    float ah = 0.0f, aw = 0.0f;
    #pragma unroll
    for (int r = 0; r < 3; ++r) {
        float su = 0.0f, sq = 0.0f;
        #pragma unroll
        for (int bb = 0; bb < 8; ++bb) {     // fixed order -> deterministic
            su += stats_part[(bb * 3 + r) * 2 + 0];
            sq += stats_part[(bb * 3 + r) * 2 + 1];
        }
        float mu = su * (1.0f / 8192.0f);
        float var = sq * (1.0f / 8192.0f) - mu * mu;
        float rs = rsqrtf(var + 1e-5f);
        int yb = (b * 3 + r) << 10;
        float yh = fmaxf((y[yb + s]       - mu) * rs * gamma[r] + beta[r], 0.0f);
        float yw = fmaxf((y[yb + 512 + s] - mu) * rs * gamma[r] + beta[r], 0.0f);
        ah = fmaf(chw[h * 3 + r], yh, ah);
        aw = fmaf(cww[h * 3 + r], yw, aw);
    }
    s_h[e] = 1.0f / (1.0f + expf(-ah));
    s_w[e] = 1.0f / (1.0f + expf(-aw));
}

// ---------------- Kernel 4: full-MFMA attention ---------------------------------
// QK^T (split MFMA) + online softmax + PV via hi/lo-split MFMA (P from LDS in
// A-frag layout, V pre-split B-frags). bh-grouped XCD swizzle for K/V L2 reuse.
__global__ __launch_bounds__(256) void attn_pv(
    const _Float16* __restrict__ Qf, const _Float16* __restrict__ Kfh,
    const _Float16* __restrict__ Kfl,
    const _Float16* __restrict__ Vfh, const _Float16* __restrict__ Vfl,
    const float* __restrict__ mask, const float* __restrict__ s_h,
    const float* __restrict__ s_w, float* __restrict__ out)
{
    __shared__ __align__(16) _Float16 Kst[2][4096];     // K frag planes
    __shared__ __align__(16) _Float16 Vst[2][4096];     // V frag planes
    __shared__ __align__(16) float P_lds[64][68];

    const int orig = blockIdx.x;
    const int xcd = orig & 7, idx = orig >> 3;
    const int bh = xcd * 12 + idx / 8, qt = idx & 7;
    const int b = bh / H_, h = bh % H_;
    const int q0 = qt * 64;
    const int tid = threadIdx.x, wave = tid >> 6, lane = tid & 63;
    const int l15 = lane & 15, g = lane >> 4;
    const int rl = wave * 16 + g * 4;                   // + reg -> local q row

    const _Float16* qb = Qf + (size_t)((bh * 32 + qt * 4 + wave) * 2) * 512 + lane * 8;
    f16x8 qa[2] = {*reinterpret_cast<const f16x8*>(qb),
                   *reinterpret_cast<const f16x8*>(qb + 512)};

    float shq[4];
    #pragma unroll
    for (int r = 0; r < 4; ++r) shq[r] = s_h[bh * S_ + q0 + rl + r];

    auto stageK = [&](int kt) {
        const _Float16* sh_ = Kfh + (size_t)((bh * 32 + kt * 4) * 2) * 512;
        const _Float16* sl_ = Kfl + (size_t)((bh * 32 + kt * 4) * 2) * 512;
        #pragma unroll
        for (int c = 0; c < 2; ++c) {
            int u = (c * 4 + wave) * 512;           // halves
            gload_lds16(&sh_[u + lane * 8], &Kst[0][u]);
            gload_lds16(&sl_[u + lane * 8], &Kst[1][u]);
        }
    };
    auto stageV = [&](int kt) {
        const _Float16* vh_ = Vfh + (size_t)((bh * 16 + kt * 2) * 4) * 512;
        const _Float16* vl_ = Vfl + (size_t)((bh * 16 + kt * 2) * 4) * 512;
        #pragma unroll
        for (int c = 0; c < 2; ++c) {
            int u = (c * 4 + wave) * 512;           // halves
            gload_lds16(&vh_[u + lane * 8], &Vst[0][u]);
            gload_lds16(&vl_[u + lane * 8], &Vst[1][u]);
        }
    };

    float m_r[4], l_r[4];
    f32x4 ctx[4];                                       // [d16 frag], D rows = g*4+r
    #pragma unroll
    for (int r = 0; r < 4; ++r) m_r[r] = -INFINITY, l_r[r] = 0.0f;
    #pragma unroll
    for (int fd = 0; fd < 4; ++fd) ctx[fd] = (f32x4){0.f, 0.f, 0.f, 0.f};

    stageK(0); stageV(0);
    __syncthreads();    // prologue drain

    for (int kt = 0; kt < 8; ++kt) {
        // --- QK^T (reads Kst) ---
        float sc[4][4];     // [fc][reg]
        #pragma unroll
        for (int fc = 0; fc < 4; ++fc) {
            f16x8 kh[2] = {*reinterpret_cast<const f16x8*>(&Kst[0][(fc * 2 + 0) * 512 + lane * 8]),
                           *reinterpret_cast<const f16x8*>(&Kst[0][(fc * 2 + 1) * 512 + lane * 8])};
            f16x8 kl[2] = {*reinterpret_cast<const f16x8*>(&Kst[1][(fc * 2 + 0) * 512 + lane * 8]),
                           *reinterpret_cast<const f16x8*>(&Kst[1][(fc * 2 + 1) * 512 + lane * 8])};
            f32x4 acc = qk_dot(qa, kh, kl);
            int col = kt * 64 + fc * 16 + l15;
            float mj  = mask[b * S_ + col];
            float swj = s_w[bh * S_ + col];
            #pragma unroll
            for (int r = 0; r < 4; ++r) {
                float t1 = acc[r] >= 2048.0f ? 1.0f : 0.0f;   // same chain as score_sums
                sc[fc][r] = acc[r] * 4.8828125e-4f + mj + t1 * (shq[r] * swj);
            }
        }
        __syncthreads();            // A: all waves done reading Kst
        if (kt < 7) stageK(kt + 1); // K loads fly under softmax + PV

        // --- online softmax (l,m chain identical to validated R6 kernel) ---
        float p[4][4], cscale[4];
        #pragma unroll
        for (int r = 0; r < 4; ++r) {
            float tmax = fmaxf(fmaxf(sc[0][r], sc[1][r]), fmaxf(sc[2][r], sc[3][r]));
            tmax = fmaxf(tmax, __shfl_xor(tmax, 1));
            tmax = fmaxf(tmax, __shfl_xor(tmax, 2));
            tmax = fmaxf(tmax, __shfl_xor(tmax, 4));
            tmax = fmaxf(tmax, __shfl_xor(tmax, 8));
            float mn = fmaxf(m_r[r], tmax);
            float ps = 0.0f;
            #pragma unroll
            for (int fc = 0; fc < 4; ++fc) { p[fc][r] = expf(sc[fc][r] - mn); ps += p[fc][r]; }
            ps += __shfl_xor(ps, 1); ps += __shfl_xor(ps, 2);
            ps += __shfl_xor(ps, 4); ps += __shfl_xor(ps, 8);
            float scale = expf(m_r[r] - mn);
            l_r[r] = l_r[r] * scale + ps;
            m_r[r] = mn;
            cscale[r] = scale;
        }
        // P to LDS (wave-private rows; no barrier needed)
        #pragma unroll
        for (int fc = 0; fc < 4; ++fc)
            #pragma unroll
            for (int r = 0; r < 4; ++r)
                P_lds[rl + r][fc * 16 + l15] = p[fc][r];

        // --- P back in A-frag layout, split hi/lo ---
        f16x8 ph[2], pl[2];
        #pragma unroll
        for (int c = 0; c < 2; ++c) {
            f32x4 pa = *reinterpret_cast<const f32x4*>(&P_lds[wave * 16 + l15][c * 32 + g * 8]);
            f32x4 pb = *reinterpret_cast<const f32x4*>(&P_lds[wave * 16 + l15][c * 32 + g * 8 + 4]);
            float pv8[8] = {pa[0], pa[1], pa[2], pa[3], pb[0], pb[1], pb[2], pb[3]};
            #pragma unroll
            for (int j = 0; j < 8; ++j) {
                _Float16 hh = (_Float16)pv8[j];
                ph[c][j] = hh;
                pl[c][j] = (_Float16)(pv8[j] - (float)hh);
            }
        }
        // rescale accumulators (rows = g*4 + r)
        #pragma unroll
        for (int fd = 0; fd < 4; ++fd)
            #pragma unroll
            for (int r = 0; r < 4; ++r) ctx[fd][r] *= cscale[r];

        // --- PV via split MFMA (reads Vst) ---
        #pragma unroll
        for (int fd = 0; fd < 4; ++fd) {
            f16x8 vh0 = *reinterpret_cast<const f16x8*>(&Vst[0][(0 * 4 + fd) * 512 + lane * 8]);
            f16x8 vl0 = *reinterpret_cast<const f16x8*>(&Vst[1][(0 * 4 + fd) * 512 + lane * 8]);
            f16x8 vh1 = *reinterpret_cast<const f16x8*>(&Vst[0][(1 * 4 + fd) * 512 + lane * 8]);
            f16x8 vl1 = *reinterpret_cast<const f16x8*>(&Vst[1][(1 * 4 + fd) * 512 + lane * 8]);
            ctx[fd] = __builtin_amdgcn_mfma_f32_16x16x32_f16(ph[0], vh0, ctx[fd], 0, 0, 0);
            ctx[fd] = __builtin_amdgcn_mfma_f32_16x16x32_f16(ph[0], vl0, ctx[fd], 0, 0, 0);
            ctx[fd] = __builtin_amdgcn_mfma_f32_16x16x32_f16(pl[0], vh0, ctx[fd], 0, 0, 0);
            ctx[fd] = __builtin_amdgcn_mfma_f32_16x16x32_f16(ph[1], vh1, ctx[fd], 0, 0, 0);
            ctx[fd] = __builtin_amdgcn_mfma_f32_16x16x32_f16(ph[1], vl1, ctx[fd], 0, 0, 0);
            ctx[fd] = __builtin_amdgcn_mfma_f32_16x16x32_f16(pl[1], vh1, ctx[fd], 0, 0, 0);
        }
        __syncthreads();            // B: drains K(kt+1); all waves done reading Vst
        if (kt < 7) stageV(kt + 1); // V loads fly under next QK^T; drained at next A
    }
    // epilogue: D layout col = l15 (d = fd*16+l15), row = g*4+r
    #pragma unroll
    for (int r = 0; r < 4; ++r) {
        int s = q0 + rl + r;
        float inv = 1.0f / l_r[r];
        float* orow = &out[((size_t)b * S_ + s) * DM_ + h * D_];
        #pragma unroll
        for (int fd = 0; fd < 4; ++fd)
            orow[fd * 16 + l15] = ctx[fd][r] * inv;
    }
}

extern "C" void kernel_launch(void* const* d_in, const int* in_sizes, int n_in,
                              void* d_out, int out_size, void* d_ws, size_t ws_size,
                              hipStream_t stream) {
    const float* X    = (const float*)d_in[0];
    const float* mask = (const float*)d_in[1];
    const float* Wq   = (const float*)d_in[2];
    const float* bq   = (const float*)d_in[3];
    const float* Wk   = (const float*)d_in[4];
    const float* bk   = (const float*)d_in[5];
    const float* Wv   = (const float*)d_in[6];
    const float* bv   = (const float*)d_in[7];
    const float* c1w  = (const float*)d_in[8];
    const float* gam  = (const float*)d_in[9];
    const float* bet  = (const float*)d_in[10];
    const float* chw  = (const float*)d_in[11];
    const float* cww  = (const float*)d_in[12];
    float* out = (float*)d_out;

    float* ws = (float*)d_ws;
    float* q  = ws;                        // 3145728 f32 (dead after prep_qk)
    float* k  = q  + 3145728;              // 3145728 f32 (dead after prep_qk)
    float* v  = k  + 3145728;              // 3145728 f32 (dead after prep_v)
    float* xh = v  + 3145728;              // 49152
    float* xw = xh + 49152;
    float* y  = xw + 49152;                // 24576
    float* sh = y  + 24576;
    float* sw = sh + 49152;
    _Float16* Xh  = (_Float16*)(sw + 49152);   // 3145728 halves
    _Float16* Xl  = Xh + 3145728;
    _Float16* Wth = Xl + 3145728;              // 1769472 halves
    _Float16* Wtl = Wth + 1769472;             // total ws ~55.6 MiB

    // Overlays on dead regions:
    _Float16* Qf  = Xh;                        // 3145728 halves (Xh dead after qkv)
    _Float16* Kfh = Xl;                        // 3145728 halves
    _Float16* Kfl = Wth;                       // 3145728 halves (spans Wth+Wtl)
    _Float16* Vfh = (_Float16*)k;              // 3145728 halves (k dead after prep_qk)
    _Float16* Vfl = Vfh + 3145728;             // 3145728 halves (fills k region exactly)
    float* stats_part = q;                     // 48 floats (q dead after prep_qk)

    hipMemsetAsync(xw, 0, 49152 * sizeof(float), stream);

    prep_x<<<1536, 256, 0, stream>>>(X, Xh, Xl);
    prep_w<<<864, 256, 0, stream>>>(Wq, Wk, Wv, Wth, Wtl);
    qkv_mfma<<<576, 256, 0, stream>>>(Xh, Xl, Wth, Wtl,
        X, Wq, bq, Wk, bk, Wv, bv, q, k, v);
    prep_qk<<<1536, 256, 0, stream>>>(q, k, Qf, Kfh, Kfl);
    prep_v<<<1536, 256, 0, stream>>>(v, Vfh, Vfl);
    score_sums<<<768, 256, 0, stream>>>(Qf, Kfh, Kfl, xh, xw);
    small_a<<<24, 256, 0, stream>>>(xh, xw, c1w, y, stats_part);
    small_b<<<96, 512, 0, stream>>>(y, stats_part, gam, bet, chw, cww, sh, sw);
    attn_pv<<<768, 256, 0, stream>>>(Qf, Kfh, Kfl, Vfh, Vfl, mask, sh, sw, out);
}